// Round 1
// baseline (777.374 us; speedup 1.0000x reference)
//
#include <hip/hip_runtime.h>

#define NN1 32768
#define NE  262144
#define FDIM 256
#define NHEADS 4
#define HIDC 64
#define IN_DIM 128
#define NB 32
#define KK1 512
#define NN2 16384   // NB*KK1
#define KK2 256
#define NN3 8192    // NB*KK2
#define OUT_DIM 256
#define BN_EPS 1e-5f
#define NEG_SLOPE 0.2f

__device__ __forceinline__ float lrelu(float x) { return x >= 0.f ? x : NEG_SLOPE * x; }

// ---------------- GEMM: C[M,N] = A[M,K] * B[K,N], row-major, M%64==0, N%64==0, K%16==0
__global__ void gemm_f32(const float* __restrict__ A, const float* __restrict__ B,
                         float* __restrict__ C, int M, int N, int K) {
  __shared__ float As[16][64];
  __shared__ float Bs[16][68];
  int tid = threadIdx.x;
  int tx = tid & 15, ty = tid >> 4;
  int bn = blockIdx.x * 64;
  int bm = blockIdx.y * 64;
  float acc[4][4];
#pragma unroll
  for (int i = 0; i < 4; i++)
#pragma unroll
    for (int j = 0; j < 4; j++) acc[i][j] = 0.f;
  int arow = tid >> 2, kg = (tid & 3) << 2;
  int bk = tid >> 4, ng = (tid & 15) << 2;
  for (int k0 = 0; k0 < K; k0 += 16) {
    float4 av = *(const float4*)(A + (size_t)(bm + arow) * K + k0 + kg);
    float4 bv = *(const float4*)(B + (size_t)(k0 + bk) * N + bn + ng);
    As[kg + 0][arow] = av.x; As[kg + 1][arow] = av.y;
    As[kg + 2][arow] = av.z; As[kg + 3][arow] = av.w;
    *(float4*)&Bs[bk][ng] = bv;
    __syncthreads();
#pragma unroll
    for (int kk = 0; kk < 16; ++kk) {
      float4 a = *(const float4*)&As[kk][ty << 2];
      float4 b = *(const float4*)&Bs[kk][tx << 2];
      float ar[4] = {a.x, a.y, a.z, a.w};
      float br[4] = {b.x, b.y, b.z, b.w};
#pragma unroll
      for (int i = 0; i < 4; i++)
#pragma unroll
        for (int j = 0; j < 4; j++) acc[i][j] = fmaf(ar[i], br[j], acc[i][j]);
    }
    __syncthreads();
  }
#pragma unroll
  for (int i = 0; i < 4; i++) {
    float4 o = make_float4(acc[i][0], acc[i][1], acc[i][2], acc[i][3]);
    *(float4*)(C + (size_t)(bm + (ty << 2) + i) * N + bn + (tx << 2)) = o;
  }
}

// per-node attention coefficients: asn[n][h] = sum_c h[n][h*64+c]*a_s[h][c]
__global__ void attn_coef_k(const float* __restrict__ h, const float* __restrict__ a_s,
                            const float* __restrict__ a_d, float* __restrict__ asn,
                            float* __restrict__ adn, int n) {
  int gid = blockIdx.x * blockDim.x + threadIdx.x;
  int node = gid >> 6, lane = threadIdx.x & 63;
  if (node >= n) return;
  const float* hp = h + (size_t)node * FDIM;
  float ps[NHEADS], pd[NHEADS];
#pragma unroll
  for (int hh = 0; hh < NHEADS; ++hh) {
    float hv = hp[hh * HIDC + lane];
    ps[hh] = hv * a_s[hh * HIDC + lane];
    pd[hh] = hv * a_d[hh * HIDC + lane];
  }
#pragma unroll
  for (int off = 32; off > 0; off >>= 1) {
#pragma unroll
    for (int hh = 0; hh < NHEADS; ++hh) {
      ps[hh] += __shfl_xor(ps[hh], off);
      pd[hh] += __shfl_xor(pd[hh], off);
    }
  }
  if (lane == 0) {
#pragma unroll
    for (int hh = 0; hh < NHEADS; ++hh) {
      asn[node * NHEADS + hh] = ps[hh];
      adn[node * NHEADS + hh] = pd[hh];
    }
  }
}

__global__ void deg_count_k(const int* __restrict__ dst, int* __restrict__ deg, int ne) {
  int e = blockIdx.x * blockDim.x + threadIdx.x;
  if (e < ne) {
    int d = dst[e];
    if (d >= 0) atomicAdd(&deg[d], 1);
  }
}

// exclusive scan of deg[0..n) -> out (and copy to out2); out[n] = total. one block of 1024.
__global__ void exscan_k(const int* __restrict__ in, int* __restrict__ out,
                         int* __restrict__ out2, int n) {
  __shared__ int wsum[16];
  __shared__ int carry;
  int tid = threadIdx.x, lane = tid & 63, wv = tid >> 6;
  if (tid == 0) carry = 0;
  __syncthreads();
  for (int base = 0; base < n; base += 1024) {
    int v = in[base + tid];
    int x = v;
#pragma unroll
    for (int off = 1; off < 64; off <<= 1) {
      int t = __shfl_up(x, off);
      if (lane >= off) x += t;
    }
    if (lane == 63) wsum[wv] = x;
    __syncthreads();
    int woff = 0;
    for (int i = 0; i < wv; i++) woff += wsum[i];
    int excl = carry + woff + x - v;
    out[base + tid] = excl;
    out2[base + tid] = excl;
    __syncthreads();
    if (tid == 0) {
      int tot = 0;
      for (int i = 0; i < 16; i++) tot += wsum[i];
      carry += tot;
    }
    __syncthreads();
  }
  if (threadIdx.x == 0) out[n] = carry;
}

__global__ void csr_fill_k(const int* __restrict__ src, const int* __restrict__ dst,
                           int* __restrict__ cursor, int* __restrict__ csrc, int ne) {
  int e = blockIdx.x * blockDim.x + threadIdx.x;
  if (e < ne) {
    int d = dst[e];
    if (d >= 0) {
      int pos = atomicAdd(&cursor[d], 1);
      csrc[pos] = src[e];
    }
  }
}

// one wave per dst node: softmax over incoming edges + self loop, accumulate alpha*h[src]
__global__ void gat_agg_k(const float* __restrict__ h, const float* __restrict__ asn,
                          const float* __restrict__ adn, const int* __restrict__ rowstart,
                          const int* __restrict__ csrc, const float* __restrict__ bias,
                          float* __restrict__ out, int n) {
  int gid = blockIdx.x * blockDim.x + threadIdx.x;
  int d = gid >> 6, lane = threadIdx.x & 63;
  if (d >= n) return;
  int beg = rowstart[d], end = rowstart[d + 1];
  float ad[NHEADS], m[NHEADS], self_l[NHEADS];
#pragma unroll
  for (int hh = 0; hh < NHEADS; ++hh) {
    ad[hh] = adn[d * NHEADS + hh];
    self_l[hh] = lrelu(asn[d * NHEADS + hh] + ad[hh]);
    m[hh] = self_l[hh];
  }
  for (int e = beg; e < end; ++e) {
    int s = csrc[e];
#pragma unroll
    for (int hh = 0; hh < NHEADS; ++hh) {
      float l = lrelu(asn[s * NHEADS + hh] + ad[hh]);
      m[hh] = fmaxf(m[hh], l);
    }
  }
  float denom[NHEADS], acc[NHEADS];
  const float* hp = h + (size_t)d * FDIM;
#pragma unroll
  for (int hh = 0; hh < NHEADS; ++hh) {
    float p = expf(self_l[hh] - m[hh]);
    denom[hh] = p;
    acc[hh] = p * hp[hh * HIDC + lane];
  }
  for (int e = beg; e < end; ++e) {
    int s = csrc[e];
    const float* hs = h + (size_t)s * FDIM;
#pragma unroll
    for (int hh = 0; hh < NHEADS; ++hh) {
      float p = expf(lrelu(asn[s * NHEADS + hh] + ad[hh]) - m[hh]);
      denom[hh] += p;
      acc[hh] = fmaf(p, hs[hh * HIDC + lane], acc[hh]);
    }
  }
  float* op = out + (size_t)d * FDIM;
#pragma unroll
  for (int hh = 0; hh < NHEADS; ++hh)
    op[hh * HIDC + lane] = acc[hh] / denom[hh] + bias[hh * HIDC + lane];
}

// in-place exact GELU + per-column sum/sumsq partials (block=256 threads, one col each)
__global__ void gelu_stats_k(float* __restrict__ x, float* __restrict__ sum,
                             float* __restrict__ sumsq, int rows_per_block) {
  int f = threadIdx.x;
  int r0 = blockIdx.x * rows_per_block;
  float s = 0.f, sq = 0.f;
  for (int r = r0; r < r0 + rows_per_block; ++r) {
    float v = x[(size_t)r * FDIM + f];
    float g = 0.5f * v * (1.0f + erff(v * 0.7071067811865476f));
    x[(size_t)r * FDIM + f] = g;
    s += g;
    sq += g * g;
  }
  atomicAdd(&sum[f], s);
  atomicAdd(&sumsq[f], sq);
}

__global__ void bn_finalize_k(const float* __restrict__ sum, const float* __restrict__ sumsq,
                              const float* __restrict__ g, const float* __restrict__ be,
                              float* __restrict__ scale, float* __restrict__ shift, float inv_n) {
  int f = threadIdx.x;
  float mean = sum[f] * inv_n;
  float var = sumsq[f] * inv_n - mean * mean;
  float sc = g[f] / sqrtf(var + BN_EPS);
  scale[f] = sc;
  shift[f] = be[f] - mean * sc;
}

__global__ void bn_apply_k(float* __restrict__ x, const float* __restrict__ scale,
                           const float* __restrict__ shift, int total) {
  int i = blockIdx.x * blockDim.x + threadIdx.x;
  if (i < total) {
    int f = i & (FDIM - 1);
    x[i] = fmaf(x[i], scale[f], shift[f]);
  }
}

__global__ void wnorm_k(const float* __restrict__ w, float* __restrict__ inv_norm) {
  __shared__ float buf[FDIM];
  int tid = threadIdx.x;
  float v = w[tid];
  buf[tid] = v * v;
  __syncthreads();
  for (int off = 128; off > 0; off >>= 1) {
    if (tid < off) buf[tid] += buf[tid + off];
    __syncthreads();
  }
  if (tid == 0) inv_norm[0] = 1.0f / sqrtf(buf[0]);
}

__global__ void score_k(const float* __restrict__ x, const float* __restrict__ w,
                        const float* __restrict__ inv_norm, float* __restrict__ score, int n) {
  int gid = blockIdx.x * blockDim.x + threadIdx.x;
  int node = gid >> 6, lane = threadIdx.x & 63;
  if (node >= n) return;
  const float* xp = x + (size_t)node * FDIM;
  float p = 0.f;
#pragma unroll
  for (int j = 0; j < 4; ++j) p = fmaf(xp[j * 64 + lane], w[j * 64 + lane], p);
#pragma unroll
  for (int off = 32; off > 0; off >>= 1) p += __shfl_xor(p, off);
  if (lane == 0) score[node] = p * inv_norm[0];
}

// per-graph bitonic sort descending (tie: lower index first); keep first KEEP
template <int NPG_T, int KEEP>
__global__ void topk_k(const float* __restrict__ score, float* __restrict__ vals,
                       int* __restrict__ gidx, int* __restrict__ inv) {
  __shared__ float sv[NPG_T];
  __shared__ int si[NPG_T];
  int tid = threadIdx.x, b = blockIdx.x;
  sv[tid] = score[b * NPG_T + tid];
  si[tid] = tid;
  for (int k = 2; k <= NPG_T; k <<= 1) {
    for (int j = k >> 1; j > 0; j >>= 1) {
      __syncthreads();
      int ixj = tid ^ j;
      if (ixj > tid) {
        float v1 = sv[tid], v2 = sv[ixj];
        int i1 = si[tid], i2 = si[ixj];
        bool before = (v1 > v2) || (v1 == v2 && i1 < i2);
        bool up = ((tid & k) == 0);
        if (up ? !before : before) {
          sv[tid] = v2; sv[ixj] = v1;
          si[tid] = i2; si[ixj] = i1;
        }
      }
    }
  }
  __syncthreads();
  if (tid < KEEP) {
    int gid = b * NPG_T + si[tid];
    int r = b * KEEP + tid;
    vals[r] = sv[tid];
    gidx[r] = gid;
    if (inv) inv[gid] = r;
  }
}

__global__ void gather_scale_k(const float* __restrict__ x, const int* __restrict__ gidx,
                               const float* __restrict__ vals, float* __restrict__ xn) {
  int r = blockIdx.x, f = threadIdx.x;
  float t = tanhf(vals[r]);
  xn[(size_t)r * FDIM + f] = x[(size_t)gidx[r] * FDIM + f] * t;
}

__global__ void readout_k(const float* __restrict__ xn, float* __restrict__ xr, int kk) {
  int b = blockIdx.x, f = threadIdx.x;
  float mx = -3.0e38f, sm = 0.f;
  const float* p = xn + (size_t)b * kk * FDIM + f;
  for (int j = 0; j < kk; ++j) {
    float v = p[(size_t)j * FDIM];
    mx = fmaxf(mx, v);
    sm += v;
  }
  xr[b * (2 * FDIM) + f] = mx;
  xr[b * (2 * FDIM) + FDIM + f] = sm / kk;
}

__global__ void remap_k(const int* __restrict__ src, const int* __restrict__ dst,
                        const int* __restrict__ inv, int* __restrict__ ns,
                        int* __restrict__ nd, int ne) {
  int e = blockIdx.x * blockDim.x + threadIdx.x;
  if (e < ne) {
    int a = inv[src[e]], bb = inv[dst[e]];
    bool ok = (a >= 0) && (bb >= 0);
    ns[e] = ok ? a : -1;
    nd[e] = ok ? bb : -1;
  }
}

__global__ void final_k(const float* __restrict__ x1, const float* __restrict__ x2,
                        const float* __restrict__ Wl, const float* __restrict__ bl,
                        float* __restrict__ out) {
  __shared__ float xs[2 * FDIM];
  int b = blockIdx.x, o = threadIdx.x;
  xs[o] = x1[b * 512 + o] + x2[b * 512 + o];
  xs[o + 256] = x1[b * 512 + 256 + o] + x2[b * 512 + 256 + o];
  __syncthreads();
  float acc = bl[o];
  const float* wp = Wl + (size_t)o * 512;
  for (int j = 0; j < 512; ++j) acc = fmaf(xs[j], wp[j], acc);
  out[b * OUT_DIM + o] = acc;
}

extern "C" void kernel_launch(void* const* d_in, const int* in_sizes, int n_in,
                              void* d_out, int out_size, void* d_ws, size_t ws_size,
                              hipStream_t stream) {
  (void)in_sizes; (void)n_in; (void)out_size; (void)ws_size;
  const float* x   = (const float*)d_in[0];
  const int* eidx  = (const int*)d_in[1];
  const int* src   = eidx;
  const int* dst   = eidx + NE;
  const float* W1  = (const float*)d_in[3];
  const float* as1 = (const float*)d_in[4];
  const float* ad1 = (const float*)d_in[5];
  const float* b1  = (const float*)d_in[6];
  const float* g1  = (const float*)d_in[7];
  const float* be1 = (const float*)d_in[8];
  const float* pw1 = (const float*)d_in[9];
  const float* W2  = (const float*)d_in[10];
  const float* as2 = (const float*)d_in[11];
  const float* ad2 = (const float*)d_in[12];
  const float* b2  = (const float*)d_in[13];
  const float* g2  = (const float*)d_in[14];
  const float* be2 = (const float*)d_in[15];
  const float* pw2 = (const float*)d_in[16];
  const float* Wl  = (const float*)d_in[17];
  const float* bl  = (const float*)d_in[18];
  float* out = (float*)d_out;

  char* wsp = (char*)d_ws;
  size_t off = 0;
  auto alloc = [&](size_t bytes) -> void* {
    void* p = wsp + off;
    off += (bytes + 255) & ~(size_t)255;
    return p;
  };
  float* h1    = (float*)alloc((size_t)NN1 * FDIM * 4);  // reused as h2
  float* out1  = (float*)alloc((size_t)NN1 * FDIM * 4);  // reused as out2
  float* xn1   = (float*)alloc((size_t)NN2 * FDIM * 4);  // reused as xn2
  float* asn   = (float*)alloc((size_t)NN1 * NHEADS * 4);
  float* adn   = (float*)alloc((size_t)NN1 * NHEADS * 4);
  int*   deg   = (int*)alloc((size_t)NN1 * 4);
  int*   rowst = (int*)alloc((size_t)(NN1 + 1) * 4);
  int*   cursor= (int*)alloc((size_t)NN1 * 4);
  int*   csrc  = (int*)alloc((size_t)NE * 4);
  int*   ns    = (int*)alloc((size_t)NE * 4);
  int*   nd    = (int*)alloc((size_t)NE * 4);
  int*   inv1  = (int*)alloc((size_t)NN1 * 4);
  float* score = (float*)alloc((size_t)NN1 * 4);
  float* vals  = (float*)alloc((size_t)NN2 * 4);
  int*   gidx  = (int*)alloc((size_t)NN2 * 4);
  float* x1r   = (float*)alloc((size_t)NB * 512 * 4);
  float* x2r   = (float*)alloc((size_t)NB * 512 * 4);
  float* bnsum = (float*)alloc(FDIM * 4);
  float* bnsq  = (float*)alloc(FDIM * 4);
  float* bnsc  = (float*)alloc(FDIM * 4);
  float* bnsh  = (float*)alloc(FDIM * 4);
  float* invnm = (float*)alloc(4);

  // ---------- layer 1 ----------
  gemm_f32<<<dim3(FDIM / 64, NN1 / 64), 256, 0, stream>>>(x, W1, h1, NN1, FDIM, IN_DIM);
  attn_coef_k<<<NN1 / 4, 256, 0, stream>>>(h1, as1, ad1, asn, adn, NN1);
  hipMemsetAsync(deg, 0, (size_t)NN1 * 4, stream);
  deg_count_k<<<NE / 256, 256, 0, stream>>>(dst, deg, NE);
  exscan_k<<<1, 1024, 0, stream>>>(deg, rowst, cursor, NN1);
  csr_fill_k<<<NE / 256, 256, 0, stream>>>(src, dst, cursor, csrc, NE);
  gat_agg_k<<<NN1 / 4, 256, 0, stream>>>(h1, asn, adn, rowst, csrc, b1, out1, NN1);
  hipMemsetAsync(bnsum, 0, FDIM * 4, stream);
  hipMemsetAsync(bnsq, 0, FDIM * 4, stream);
  gelu_stats_k<<<NN1 / 128, 256, 0, stream>>>(out1, bnsum, bnsq, 128);
  bn_finalize_k<<<1, 256, 0, stream>>>(bnsum, bnsq, g1, be1, bnsc, bnsh, 1.0f / NN1);
  bn_apply_k<<<(NN1 * FDIM) / 256, 256, 0, stream>>>(out1, bnsc, bnsh, NN1 * FDIM);
  // ---------- pool 1 ----------
  wnorm_k<<<1, 256, 0, stream>>>(pw1, invnm);
  score_k<<<NN1 / 4, 256, 0, stream>>>(out1, pw1, invnm, score, NN1);
  hipMemsetAsync(inv1, 0xFF, (size_t)NN1 * 4, stream);
  topk_k<1024, 512><<<NB, 1024, 0, stream>>>(score, vals, gidx, inv1);
  gather_scale_k<<<NN2, 256, 0, stream>>>(out1, gidx, vals, xn1);
  readout_k<<<NB, 256, 0, stream>>>(xn1, x1r, KK1);
  remap_k<<<NE / 256, 256, 0, stream>>>(src, dst, inv1, ns, nd, NE);
  // ---------- layer 2 ----------
  float* h2 = h1;
  float* out2 = out1;
  gemm_f32<<<dim3(FDIM / 64, NN2 / 64), 256, 0, stream>>>(xn1, W2, h2, NN2, FDIM, FDIM);
  attn_coef_k<<<NN2 / 4, 256, 0, stream>>>(h2, as2, ad2, asn, adn, NN2);
  hipMemsetAsync(deg, 0, (size_t)NN2 * 4, stream);
  deg_count_k<<<NE / 256, 256, 0, stream>>>(nd, deg, NE);
  exscan_k<<<1, 1024, 0, stream>>>(deg, rowst, cursor, NN2);
  csr_fill_k<<<NE / 256, 256, 0, stream>>>(ns, nd, cursor, csrc, NE);
  gat_agg_k<<<NN2 / 4, 256, 0, stream>>>(h2, asn, adn, rowst, csrc, b2, out2, NN2);
  hipMemsetAsync(bnsum, 0, FDIM * 4, stream);
  hipMemsetAsync(bnsq, 0, FDIM * 4, stream);
  gelu_stats_k<<<NN2 / 128, 256, 0, stream>>>(out2, bnsum, bnsq, 128);
  bn_finalize_k<<<1, 256, 0, stream>>>(bnsum, bnsq, g2, be2, bnsc, bnsh, 1.0f / NN2);
  bn_apply_k<<<(NN2 * FDIM) / 256, 256, 0, stream>>>(out2, bnsc, bnsh, NN2 * FDIM);
  // ---------- pool 2 ----------
  wnorm_k<<<1, 256, 0, stream>>>(pw2, invnm);
  score_k<<<NN2 / 4, 256, 0, stream>>>(out2, pw2, invnm, score, NN2);
  topk_k<512, 256><<<NB, 512, 0, stream>>>(score, vals, gidx, nullptr);
  float* xn2 = xn1;
  gather_scale_k<<<NN3, 256, 0, stream>>>(out2, gidx, vals, xn2);
  readout_k<<<NB, 256, 0, stream>>>(xn2, x2r, KK2);
  // ---------- final ----------
  final_k<<<NB, 256, 0, stream>>>(x1r, x2r, Wl, bl, out);
}

// Round 2
// 609.256 us; speedup vs baseline: 1.2759x; 1.2759x over previous
//
#include <hip/hip_runtime.h>

#define NN1 32768
#define NE  262144
#define FDIM 256
#define NHEADS 4
#define HIDC 64
#define IN_DIM 128
#define NB 32
#define KK1 512
#define NN2 16384   // NB*KK1
#define KK2 256
#define NN3 8192    // NB*KK2
#define OUT_DIM 256
#define BN_EPS 1e-5f
#define NEG_SLOPE 0.2f

__device__ __forceinline__ float lrelu(float x) { return x >= 0.f ? x : NEG_SLOPE * x; }

// ---------------- GEMM: C[M,N] = A[M,K] * B[K,N], row-major, M%64==0, N%64==0, K%16==0
__global__ void gemm_f32(const float* __restrict__ A, const float* __restrict__ B,
                         float* __restrict__ C, int M, int N, int K) {
  __shared__ float As[16][64];
  __shared__ float Bs[16][68];
  int tid = threadIdx.x;
  int tx = tid & 15, ty = tid >> 4;
  int bn = blockIdx.x * 64;
  int bm = blockIdx.y * 64;
  float acc[4][4];
#pragma unroll
  for (int i = 0; i < 4; i++)
#pragma unroll
    for (int j = 0; j < 4; j++) acc[i][j] = 0.f;
  int arow = tid >> 2, kg = (tid & 3) << 2;
  int bk = tid >> 4, ng = (tid & 15) << 2;
  for (int k0 = 0; k0 < K; k0 += 16) {
    float4 av = *(const float4*)(A + (size_t)(bm + arow) * K + k0 + kg);
    float4 bv = *(const float4*)(B + (size_t)(k0 + bk) * N + bn + ng);
    As[kg + 0][arow] = av.x; As[kg + 1][arow] = av.y;
    As[kg + 2][arow] = av.z; As[kg + 3][arow] = av.w;
    *(float4*)&Bs[bk][ng] = bv;
    __syncthreads();
#pragma unroll
    for (int kk = 0; kk < 16; ++kk) {
      float4 a = *(const float4*)&As[kk][ty << 2];
      float4 b = *(const float4*)&Bs[kk][tx << 2];
      float ar[4] = {a.x, a.y, a.z, a.w};
      float br[4] = {b.x, b.y, b.z, b.w};
#pragma unroll
      for (int i = 0; i < 4; i++)
#pragma unroll
        for (int j = 0; j < 4; j++) acc[i][j] = fmaf(ar[i], br[j], acc[i][j]);
    }
    __syncthreads();
  }
#pragma unroll
  for (int i = 0; i < 4; i++) {
    float4 o = make_float4(acc[i][0], acc[i][1], acc[i][2], acc[i][3]);
    *(float4*)(C + (size_t)(bm + (ty << 2) + i) * N + bn + (tx << 2)) = o;
  }
}

// per-node attention coefficients: asn[n][h] = sum_c h[n][h*64+c]*a_s[h][c]
__global__ void attn_coef_k(const float* __restrict__ h, const float* __restrict__ a_s,
                            const float* __restrict__ a_d, float* __restrict__ asn,
                            float* __restrict__ adn, int n) {
  int gid = blockIdx.x * blockDim.x + threadIdx.x;
  int node = gid >> 6, lane = threadIdx.x & 63;
  if (node >= n) return;
  const float* hp = h + (size_t)node * FDIM;
  float ps[NHEADS], pd[NHEADS];
#pragma unroll
  for (int hh = 0; hh < NHEADS; ++hh) {
    float hv = hp[hh * HIDC + lane];
    ps[hh] = hv * a_s[hh * HIDC + lane];
    pd[hh] = hv * a_d[hh * HIDC + lane];
  }
#pragma unroll
  for (int off = 32; off > 0; off >>= 1) {
#pragma unroll
    for (int hh = 0; hh < NHEADS; ++hh) {
      ps[hh] += __shfl_xor(ps[hh], off);
      pd[hh] += __shfl_xor(pd[hh], off);
    }
  }
  if (lane == 0) {
#pragma unroll
    for (int hh = 0; hh < NHEADS; ++hh) {
      asn[node * NHEADS + hh] = ps[hh];
      adn[node * NHEADS + hh] = pd[hh];
    }
  }
}

__global__ void deg_count_k(const int* __restrict__ dst, int* __restrict__ deg, int ne) {
  int e = blockIdx.x * blockDim.x + threadIdx.x;
  if (e < ne) {
    int d = dst[e];
    if (d >= 0) atomicAdd(&deg[d], 1);
  }
}

// exclusive scan of deg[0..n) -> out (and copy to out2); out[n] = total. one block of 1024.
__global__ void exscan_k(const int* __restrict__ in, int* __restrict__ out,
                         int* __restrict__ out2, int n) {
  __shared__ int wsum[16];
  __shared__ int carry;
  int tid = threadIdx.x, lane = tid & 63, wv = tid >> 6;
  if (tid == 0) carry = 0;
  __syncthreads();
  for (int base = 0; base < n; base += 1024) {
    int v = in[base + tid];
    int x = v;
#pragma unroll
    for (int off = 1; off < 64; off <<= 1) {
      int t = __shfl_up(x, off);
      if (lane >= off) x += t;
    }
    if (lane == 63) wsum[wv] = x;
    __syncthreads();
    int woff = 0;
    for (int i = 0; i < wv; i++) woff += wsum[i];
    int excl = carry + woff + x - v;
    out[base + tid] = excl;
    out2[base + tid] = excl;
    __syncthreads();
    if (tid == 0) {
      int tot = 0;
      for (int i = 0; i < 16; i++) tot += wsum[i];
      carry += tot;
    }
    __syncthreads();
  }
  if (threadIdx.x == 0) out[n] = carry;
}

__global__ void csr_fill_k(const int* __restrict__ src, const int* __restrict__ dst,
                           int* __restrict__ cursor, int* __restrict__ csrc, int ne) {
  int e = blockIdx.x * blockDim.x + threadIdx.x;
  if (e < ne) {
    int d = dst[e];
    if (d >= 0) {
      int pos = atomicAdd(&cursor[d], 1);
      csrc[pos] = src[e];
    }
  }
}

// one wave per dst node: softmax over incoming edges + self loop, accumulate alpha*h[src]
__global__ void gat_agg_k(const float* __restrict__ h, const float* __restrict__ asn,
                          const float* __restrict__ adn, const int* __restrict__ rowstart,
                          const int* __restrict__ csrc, const float* __restrict__ bias,
                          float* __restrict__ out, int n) {
  int gid = blockIdx.x * blockDim.x + threadIdx.x;
  int d = gid >> 6, lane = threadIdx.x & 63;
  if (d >= n) return;
  int beg = rowstart[d], end = rowstart[d + 1];
  float ad[NHEADS], m[NHEADS], self_l[NHEADS];
#pragma unroll
  for (int hh = 0; hh < NHEADS; ++hh) {
    ad[hh] = adn[d * NHEADS + hh];
    self_l[hh] = lrelu(asn[d * NHEADS + hh] + ad[hh]);
    m[hh] = self_l[hh];
  }
  for (int e = beg; e < end; ++e) {
    int s = csrc[e];
#pragma unroll
    for (int hh = 0; hh < NHEADS; ++hh) {
      float l = lrelu(asn[s * NHEADS + hh] + ad[hh]);
      m[hh] = fmaxf(m[hh], l);
    }
  }
  float denom[NHEADS], acc[NHEADS];
  const float* hp = h + (size_t)d * FDIM;
#pragma unroll
  for (int hh = 0; hh < NHEADS; ++hh) {
    float p = expf(self_l[hh] - m[hh]);
    denom[hh] = p;
    acc[hh] = p * hp[hh * HIDC + lane];
  }
  for (int e = beg; e < end; ++e) {
    int s = csrc[e];
    const float* hs = h + (size_t)s * FDIM;
#pragma unroll
    for (int hh = 0; hh < NHEADS; ++hh) {
      float p = expf(lrelu(asn[s * NHEADS + hh] + ad[hh]) - m[hh]);
      denom[hh] += p;
      acc[hh] = fmaf(p, hs[hh * HIDC + lane], acc[hh]);
    }
  }
  float* op = out + (size_t)d * FDIM;
#pragma unroll
  for (int hh = 0; hh < NHEADS; ++hh)
    op[hh * HIDC + lane] = acc[hh] / denom[hh] + bias[hh * HIDC + lane];
}

// in-place exact GELU + per-column sum/sumsq partials (block=256 threads, one col each)
__global__ void gelu_stats_k(float* __restrict__ x, float* __restrict__ sum,
                             float* __restrict__ sumsq, int rows_per_block) {
  int f = threadIdx.x;
  int r0 = blockIdx.x * rows_per_block;
  float s = 0.f, sq = 0.f;
  for (int r = r0; r < r0 + rows_per_block; ++r) {
    float v = x[(size_t)r * FDIM + f];
    float g = 0.5f * v * (1.0f + erff(v * 0.7071067811865476f));
    x[(size_t)r * FDIM + f] = g;
    s += g;
    sq += g * g;
  }
  atomicAdd(&sum[f], s);
  atomicAdd(&sumsq[f], sq);
}

__global__ void bn_finalize_k(const float* __restrict__ sum, const float* __restrict__ sumsq,
                              const float* __restrict__ g, const float* __restrict__ be,
                              float* __restrict__ scale, float* __restrict__ shift, float inv_n) {
  int f = threadIdx.x;
  float mean = sum[f] * inv_n;
  float var = sumsq[f] * inv_n - mean * mean;
  float sc = g[f] / sqrtf(var + BN_EPS);
  scale[f] = sc;
  shift[f] = be[f] - mean * sc;
}

__global__ void bn_apply_k(float* __restrict__ x, const float* __restrict__ scale,
                           const float* __restrict__ shift, int total) {
  int i = blockIdx.x * blockDim.x + threadIdx.x;
  if (i < total) {
    int f = i & (FDIM - 1);
    x[i] = fmaf(x[i], scale[f], shift[f]);
  }
}

// score = (x.w)/||w||, ||w|| computed in-wave (w is 256 floats, L1-resident)
__global__ void score_k(const float* __restrict__ x, const float* __restrict__ w,
                        float* __restrict__ score, int n) {
  int gid = blockIdx.x * blockDim.x + threadIdx.x;
  int node = gid >> 6, lane = threadIdx.x & 63;
  if (node >= n) return;
  const float* xp = x + (size_t)node * FDIM;
  float p = 0.f, nw = 0.f;
#pragma unroll
  for (int j = 0; j < 4; ++j) {
    float wv = w[j * 64 + lane];
    p = fmaf(xp[j * 64 + lane], wv, p);
    nw = fmaf(wv, wv, nw);
  }
#pragma unroll
  for (int off = 32; off > 0; off >>= 1) {
    p += __shfl_xor(p, off);
    nw += __shfl_xor(nw, off);
  }
  if (lane == 0) score[node] = p / sqrtf(nw);
}

// per-graph bitonic sort descending (tie: lower index first); keep first KEEP
template <int NPG_T, int KEEP>
__global__ void topk_k(const float* __restrict__ score, float* __restrict__ vals,
                       int* __restrict__ gidx, int* __restrict__ inv) {
  __shared__ float sv[NPG_T];
  __shared__ int si[NPG_T];
  int tid = threadIdx.x, b = blockIdx.x;
  sv[tid] = score[b * NPG_T + tid];
  si[tid] = tid;
  for (int k = 2; k <= NPG_T; k <<= 1) {
    for (int j = k >> 1; j > 0; j >>= 1) {
      __syncthreads();
      int ixj = tid ^ j;
      if (ixj > tid) {
        float v1 = sv[tid], v2 = sv[ixj];
        int i1 = si[tid], i2 = si[ixj];
        bool before = (v1 > v2) || (v1 == v2 && i1 < i2);
        bool up = ((tid & k) == 0);
        if (up ? !before : before) {
          sv[tid] = v2; sv[ixj] = v1;
          si[tid] = i2; si[ixj] = i1;
        }
      }
    }
  }
  __syncthreads();
  if (tid < KEEP) {
    int gid = b * NPG_T + si[tid];
    int r = b * KEEP + tid;
    vals[r] = sv[tid];
    gidx[r] = gid;
    if (inv) inv[gid] = r;
  }
}

__global__ void gather_scale_k(const float* __restrict__ x, const int* __restrict__ gidx,
                               const float* __restrict__ vals, float* __restrict__ xn) {
  int r = blockIdx.x, f = threadIdx.x;
  float t = tanhf(vals[r]);
  xn[(size_t)r * FDIM + f] = x[(size_t)gidx[r] * FDIM + f] * t;
}

// readout phase 1: each block reduces ROWS rows of one graph -> partial max/sum
#define RD_ROWS 16
__global__ void readout_part_k(const float* __restrict__ xn, float* __restrict__ pmax,
                               float* __restrict__ psum, int kk, int seg_per_graph) {
  int blk = blockIdx.x, f = threadIdx.x;
  int b = blk / seg_per_graph, s = blk - b * seg_per_graph;
  const float* p = xn + ((size_t)b * kk + (size_t)s * RD_ROWS) * FDIM + f;
  float mx = -3.0e38f, sm = 0.f;
#pragma unroll
  for (int j = 0; j < RD_ROWS; ++j) {
    float v = p[(size_t)j * FDIM];
    mx = fmaxf(mx, v);
    sm += v;
  }
  pmax[(size_t)blk * FDIM + f] = mx;
  psum[(size_t)blk * FDIM + f] = sm;
}

__global__ void readout_final_k(const float* __restrict__ pmax, const float* __restrict__ psum,
                                float* __restrict__ xr, int seg_per_graph, float inv_k) {
  int b = blockIdx.x, f = threadIdx.x;
  float mx = -3.0e38f, sm = 0.f;
  for (int s = 0; s < seg_per_graph; ++s) {
    mx = fmaxf(mx, pmax[((size_t)b * seg_per_graph + s) * FDIM + f]);
    sm += psum[((size_t)b * seg_per_graph + s) * FDIM + f];
  }
  xr[b * (2 * FDIM) + f] = mx;
  xr[b * (2 * FDIM) + FDIM + f] = sm * inv_k;
}

__global__ void remap_k(const int* __restrict__ src, const int* __restrict__ dst,
                        const int* __restrict__ inv, int* __restrict__ ns,
                        int* __restrict__ nd, int ne) {
  int e = blockIdx.x * blockDim.x + threadIdx.x;
  if (e < ne) {
    int a = inv[src[e]], bb = inv[dst[e]];
    bool ok = (a >= 0) && (bb >= 0);
    ns[e] = ok ? a : -1;
    nd[e] = ok ? bb : -1;
  }
}

__global__ void final_k(const float* __restrict__ x1, const float* __restrict__ x2,
                        const float* __restrict__ Wl, const float* __restrict__ bl,
                        float* __restrict__ out) {
  __shared__ float xs[2 * FDIM];
  int b = blockIdx.x, o = threadIdx.x;
  xs[o] = x1[b * 512 + o] + x2[b * 512 + o];
  xs[o + 256] = x1[b * 512 + 256 + o] + x2[b * 512 + 256 + o];
  __syncthreads();
  float acc = bl[o];
  const float* wp = Wl + (size_t)o * 512;
  for (int j = 0; j < 512; ++j) acc = fmaf(xs[j], wp[j], acc);
  out[b * OUT_DIM + o] = acc;
}

extern "C" void kernel_launch(void* const* d_in, const int* in_sizes, int n_in,
                              void* d_out, int out_size, void* d_ws, size_t ws_size,
                              hipStream_t stream) {
  (void)in_sizes; (void)n_in; (void)out_size; (void)ws_size;
  const float* x   = (const float*)d_in[0];
  const int* eidx  = (const int*)d_in[1];
  const int* src   = eidx;
  const int* dst   = eidx + NE;
  const float* W1  = (const float*)d_in[3];
  const float* as1 = (const float*)d_in[4];
  const float* ad1 = (const float*)d_in[5];
  const float* b1  = (const float*)d_in[6];
  const float* g1  = (const float*)d_in[7];
  const float* be1 = (const float*)d_in[8];
  const float* pw1 = (const float*)d_in[9];
  const float* W2  = (const float*)d_in[10];
  const float* as2 = (const float*)d_in[11];
  const float* ad2 = (const float*)d_in[12];
  const float* b2  = (const float*)d_in[13];
  const float* g2  = (const float*)d_in[14];
  const float* be2 = (const float*)d_in[15];
  const float* pw2 = (const float*)d_in[16];
  const float* Wl  = (const float*)d_in[17];
  const float* bl  = (const float*)d_in[18];
  float* out = (float*)d_out;

  char* wsp = (char*)d_ws;
  size_t off = 0;
  auto alloc = [&](size_t bytes) -> void* {
    void* p = wsp + off;
    off += (bytes + 255) & ~(size_t)255;
    return p;
  };
  float* h1    = (float*)alloc((size_t)NN1 * FDIM * 4);  // reused as h2
  float* out1  = (float*)alloc((size_t)NN1 * FDIM * 4);  // reused as out2
  float* xn1   = (float*)alloc((size_t)NN2 * FDIM * 4);  // reused as xn2
  float* asn   = (float*)alloc((size_t)NN1 * NHEADS * 4);
  float* adn   = (float*)alloc((size_t)NN1 * NHEADS * 4);
  int*   deg   = (int*)alloc((size_t)NN1 * 4);
  int*   rowst = (int*)alloc((size_t)(NN1 + 1) * 4);
  int*   cursor= (int*)alloc((size_t)NN1 * 4);
  int*   csrc  = (int*)alloc((size_t)NE * 4);
  int*   ns    = (int*)alloc((size_t)NE * 4);
  int*   nd    = (int*)alloc((size_t)NE * 4);
  int*   inv1  = (int*)alloc((size_t)NN1 * 4);
  float* score = (float*)alloc((size_t)NN1 * 4);
  float* vals  = (float*)alloc((size_t)NN2 * 4);
  int*   gidx  = (int*)alloc((size_t)NN2 * 4);
  float* x1r   = (float*)alloc((size_t)NB * 512 * 4);
  float* x2r   = (float*)alloc((size_t)NB * 512 * 4);
  float* bnsum = (float*)alloc(FDIM * 4);   // NOTE: bnsq must stay adjacent (single memset)
  float* bnsq  = (float*)alloc(FDIM * 4);
  float* bnsc  = (float*)alloc(FDIM * 4);
  float* bnsh  = (float*)alloc(FDIM * 4);
  float* pmax  = (float*)alloc((size_t)(NN2 / RD_ROWS) * FDIM * 4);
  float* psum  = (float*)alloc((size_t)(NN2 / RD_ROWS) * FDIM * 4);

  // ---------- layer 1 ----------
  gemm_f32<<<dim3(FDIM / 64, NN1 / 64), 256, 0, stream>>>(x, W1, h1, NN1, FDIM, IN_DIM);
  attn_coef_k<<<NN1 / 4, 256, 0, stream>>>(h1, as1, ad1, asn, adn, NN1);
  hipMemsetAsync(deg, 0, (size_t)NN1 * 4, stream);
  deg_count_k<<<NE / 256, 256, 0, stream>>>(dst, deg, NE);
  exscan_k<<<1, 1024, 0, stream>>>(deg, rowst, cursor, NN1);
  csr_fill_k<<<NE / 256, 256, 0, stream>>>(src, dst, cursor, csrc, NE);
  gat_agg_k<<<NN1 / 4, 256, 0, stream>>>(h1, asn, adn, rowst, csrc, b1, out1, NN1);
  hipMemsetAsync(bnsum, 0, FDIM * 2 * 4, stream);  // bnsum + bnsq contiguous
  gelu_stats_k<<<NN1 / 128, 256, 0, stream>>>(out1, bnsum, bnsq, 128);
  bn_finalize_k<<<1, 256, 0, stream>>>(bnsum, bnsq, g1, be1, bnsc, bnsh, 1.0f / NN1);
  bn_apply_k<<<(NN1 * FDIM) / 256, 256, 0, stream>>>(out1, bnsc, bnsh, NN1 * FDIM);
  // ---------- pool 1 ----------
  score_k<<<NN1 / 4, 256, 0, stream>>>(out1, pw1, score, NN1);
  hipMemsetAsync(inv1, 0xFF, (size_t)NN1 * 4, stream);
  topk_k<1024, 512><<<NB, 1024, 0, stream>>>(score, vals, gidx, inv1);
  gather_scale_k<<<NN2, 256, 0, stream>>>(out1, gidx, vals, xn1);
  readout_part_k<<<NN2 / RD_ROWS, 256, 0, stream>>>(xn1, pmax, psum, KK1, KK1 / RD_ROWS);
  readout_final_k<<<NB, 256, 0, stream>>>(pmax, psum, x1r, KK1 / RD_ROWS, 1.0f / KK1);
  remap_k<<<NE / 256, 256, 0, stream>>>(src, dst, inv1, ns, nd, NE);
  // ---------- layer 2 ----------
  float* h2 = h1;
  float* out2 = out1;
  gemm_f32<<<dim3(FDIM / 64, NN2 / 64), 256, 0, stream>>>(xn1, W2, h2, NN2, FDIM, FDIM);
  attn_coef_k<<<NN2 / 4, 256, 0, stream>>>(h2, as2, ad2, asn, adn, NN2);
  hipMemsetAsync(deg, 0, (size_t)NN2 * 4, stream);
  deg_count_k<<<NE / 256, 256, 0, stream>>>(nd, deg, NE);
  exscan_k<<<1, 1024, 0, stream>>>(deg, rowst, cursor, NN2);
  csr_fill_k<<<NE / 256, 256, 0, stream>>>(ns, nd, cursor, csrc, NE);
  gat_agg_k<<<NN2 / 4, 256, 0, stream>>>(h2, asn, adn, rowst, csrc, b2, out2, NN2);
  hipMemsetAsync(bnsum, 0, FDIM * 2 * 4, stream);
  gelu_stats_k<<<NN2 / 128, 256, 0, stream>>>(out2, bnsum, bnsq, 128);
  bn_finalize_k<<<1, 256, 0, stream>>>(bnsum, bnsq, g2, be2, bnsc, bnsh, 1.0f / NN2);
  bn_apply_k<<<(NN2 * FDIM) / 256, 256, 0, stream>>>(out2, bnsc, bnsh, NN2 * FDIM);
  // ---------- pool 2 ----------
  score_k<<<NN2 / 4, 256, 0, stream>>>(out2, pw2, score, NN2);
  topk_k<512, 256><<<NB, 512, 0, stream>>>(score, vals, gidx, nullptr);
  float* xn2 = xn1;
  gather_scale_k<<<NN3, 256, 0, stream>>>(out2, gidx, vals, xn2);
  readout_part_k<<<NN3 / RD_ROWS, 256, 0, stream>>>(xn2, pmax, psum, KK2, KK2 / RD_ROWS);
  readout_final_k<<<NB, 256, 0, stream>>>(pmax, psum, x2r, KK2 / RD_ROWS, 1.0f / KK2);
  // ---------- final ----------
  final_k<<<NB, 256, 0, stream>>>(x1r, x2r, Wl, bl, out);
}

// Round 3
// 508.011 us; speedup vs baseline: 1.5302x; 1.1993x over previous
//
#include <hip/hip_runtime.h>

#define NN1 32768
#define NE  262144
#define FDIM 256
#define NHEADS 4
#define HIDC 64
#define IN_DIM 128
#define NB 32
#define KK1 512
#define NN2 16384   // NB*KK1
#define KK2 256
#define NN3 8192    // NB*KK2
#define OUT_DIM 256
#define BN_EPS 1e-5f
#define NEG_SLOPE 0.2f

__device__ __forceinline__ float lrelu(float x) { return x >= 0.f ? x : NEG_SLOPE * x; }

// ---------------- GEMM: C[M,N] = A[M,K] * B[K,N], 128x128 tile, 8x8 per thread
__global__ void gemm128_f32(const float* __restrict__ A, const float* __restrict__ B,
                            float* __restrict__ C, int M, int N, int K) {
  __shared__ float As[8][128];
  __shared__ float Bs[8][128];
  int tid = threadIdx.x;
  int tx = tid & 15, ty = tid >> 4;        // 16 x 16 threads
  int bn = blockIdx.x * 128, bm = blockIdx.y * 128;
  float acc[8][8];
#pragma unroll
  for (int i = 0; i < 8; i++)
#pragma unroll
    for (int j = 0; j < 8; j++) acc[i][j] = 0.f;
  int arow = tid >> 1, akg = (tid & 1) * 4;   // A: 128 rows x 8 k
  int brow = tid >> 5, bcol = (tid & 31) * 4; // B: 8 rows x 128 cols
  for (int k0 = 0; k0 < K; k0 += 8) {
    float4 av = *(const float4*)(A + (size_t)(bm + arow) * K + k0 + akg);
    float4 bv = *(const float4*)(B + (size_t)(k0 + brow) * N + bn + bcol);
    As[akg + 0][arow] = av.x; As[akg + 1][arow] = av.y;
    As[akg + 2][arow] = av.z; As[akg + 3][arow] = av.w;
    *(float4*)&Bs[brow][bcol] = bv;
    __syncthreads();
#pragma unroll
    for (int kk = 0; kk < 8; ++kk) {
      float4 a0 = *(const float4*)&As[kk][ty * 8];
      float4 a1 = *(const float4*)&As[kk][ty * 8 + 4];
      float4 b0 = *(const float4*)&Bs[kk][tx * 8];
      float4 b1 = *(const float4*)&Bs[kk][tx * 8 + 4];
      float ar[8] = {a0.x, a0.y, a0.z, a0.w, a1.x, a1.y, a1.z, a1.w};
      float br[8] = {b0.x, b0.y, b0.z, b0.w, b1.x, b1.y, b1.z, b1.w};
#pragma unroll
      for (int i = 0; i < 8; i++)
#pragma unroll
        for (int j = 0; j < 8; j++) acc[i][j] = fmaf(ar[i], br[j], acc[i][j]);
    }
    __syncthreads();
  }
#pragma unroll
  for (int i = 0; i < 8; i++) {
    float* cp = C + (size_t)(bm + ty * 8 + i) * N + bn + tx * 8;
    *(float4*)cp = make_float4(acc[i][0], acc[i][1], acc[i][2], acc[i][3]);
    *(float4*)(cp + 4) = make_float4(acc[i][4], acc[i][5], acc[i][6], acc[i][7]);
  }
}

// per-node attention coefficients: asn[n][h] = sum_c h[n][h*64+c]*a_s[h][c]
__global__ void attn_coef_k(const float* __restrict__ h, const float* __restrict__ a_s,
                            const float* __restrict__ a_d, float* __restrict__ asn,
                            float* __restrict__ adn, int n) {
  int gid = blockIdx.x * blockDim.x + threadIdx.x;
  int node = gid >> 6, lane = threadIdx.x & 63;
  if (node >= n) return;
  const float* hp = h + (size_t)node * FDIM;
  float ps[NHEADS], pd[NHEADS];
#pragma unroll
  for (int hh = 0; hh < NHEADS; ++hh) {
    float hv = hp[hh * HIDC + lane];
    ps[hh] = hv * a_s[hh * HIDC + lane];
    pd[hh] = hv * a_d[hh * HIDC + lane];
  }
#pragma unroll
  for (int off = 32; off > 0; off >>= 1) {
#pragma unroll
    for (int hh = 0; hh < NHEADS; ++hh) {
      ps[hh] += __shfl_xor(ps[hh], off);
      pd[hh] += __shfl_xor(pd[hh], off);
    }
  }
  if (lane == 0) {
#pragma unroll
    for (int hh = 0; hh < NHEADS; ++hh) {
      asn[node * NHEADS + hh] = ps[hh];
      adn[node * NHEADS + hh] = pd[hh];
    }
  }
}

__global__ void deg_count_k(const int* __restrict__ dst, int* __restrict__ deg, int ne) {
  int e = blockIdx.x * blockDim.x + threadIdx.x;
  if (e < ne) {
    int d = dst[e];
    if (d >= 0) atomicAdd(&deg[d], 1);
  }
}

// 2-level exclusive scan: phase 1 scans 1024-blocks, phase 2 adds block offsets
__global__ void exscan1_k(const int* __restrict__ in, int* __restrict__ outv,
                          int* __restrict__ bsum) {
  __shared__ int wsum[16];
  int tid = threadIdx.x, lane = tid & 63, wv = tid >> 6;
  int base = blockIdx.x * 1024;
  int v = in[base + tid];
  int x = v;
#pragma unroll
  for (int off = 1; off < 64; off <<= 1) {
    int t = __shfl_up(x, off);
    if (lane >= off) x += t;
  }
  if (lane == 63) wsum[wv] = x;
  __syncthreads();
  int woff = 0;
  for (int i = 0; i < wv; i++) woff += wsum[i];
  outv[base + tid] = woff + x - v;
  if (tid == 1023) bsum[blockIdx.x] = woff + x;
}

__global__ void exscan2_k(const int* __restrict__ outv, const int* __restrict__ bsum,
                          int* __restrict__ rowstart, int* __restrict__ cursor,
                          int nblocks, int n) {
  __shared__ int goff;
  int b = blockIdx.x, tid = threadIdx.x;
  if (tid == 0) {
    int s = 0;
    for (int i = 0; i < b; i++) s += bsum[i];
    goff = s;
    if (b == nblocks - 1) rowstart[n] = s + bsum[b];
  }
  __syncthreads();
  int val = outv[b * 1024 + tid] + goff;
  rowstart[b * 1024 + tid] = val;
  cursor[b * 1024 + tid] = val;
}

// CSR fill + per-edge softmax numerator exp(lrelu(asn[s]+adn[d])) (no max shift)
__global__ void csr_fill_p_k(const int* __restrict__ src, const int* __restrict__ dst,
                             int* __restrict__ cursor, const float4* __restrict__ asn4,
                             const float4* __restrict__ adn4, int* __restrict__ csrc,
                             float4* __restrict__ pexp, int ne) {
  int e = blockIdx.x * blockDim.x + threadIdx.x;
  if (e >= ne) return;
  int d = dst[e];
  if (d < 0) return;
  int s = src[e];
  int pos = atomicAdd(&cursor[d], 1);
  csrc[pos] = s;
  float4 a = asn4[s], b = adn4[d];
  float4 p;
  p.x = expf(lrelu(a.x + b.x));
  p.y = expf(lrelu(a.y + b.y));
  p.z = expf(lrelu(a.z + b.z));
  p.w = expf(lrelu(a.w + b.w));
  pexp[pos] = p;
}

// one wave per dst node, single pass: denom += p, acc += p*h[src]
__global__ void gat_agg_k(const float* __restrict__ h, const float4* __restrict__ asn4,
                          const float4* __restrict__ adn4, const int* __restrict__ rowstart,
                          const int* __restrict__ csrc, const float4* __restrict__ pexp,
                          const float* __restrict__ bias, float* __restrict__ out, int n) {
  int lane = threadIdx.x & 63;
  int d = __builtin_amdgcn_readfirstlane(blockIdx.x * 4 + (threadIdx.x >> 6));
  if (d >= n) return;
  int beg = rowstart[d], end = rowstart[d + 1];
  float4 sa = asn4[d], sb = adn4[d];
  float p0 = expf(lrelu(sa.x + sb.x));
  float p1 = expf(lrelu(sa.y + sb.y));
  float p2 = expf(lrelu(sa.z + sb.z));
  float p3 = expf(lrelu(sa.w + sb.w));
  const float* hp = h + (size_t)d * FDIM;
  float de0 = p0, de1 = p1, de2 = p2, de3 = p3;
  float a0 = p0 * hp[lane];
  float a1 = p1 * hp[64 + lane];
  float a2 = p2 * hp[128 + lane];
  float a3 = p3 * hp[192 + lane];
  for (int e = beg; e < end; ++e) {
    int s = csrc[e];
    float4 p = pexp[e];
    const float* hs = h + (size_t)s * FDIM;
    de0 += p.x; de1 += p.y; de2 += p.z; de3 += p.w;
    a0 = fmaf(p.x, hs[lane], a0);
    a1 = fmaf(p.y, hs[64 + lane], a1);
    a2 = fmaf(p.z, hs[128 + lane], a2);
    a3 = fmaf(p.w, hs[192 + lane], a3);
  }
  float* op = out + (size_t)d * FDIM;
  op[lane]       = a0 / de0 + bias[lane];
  op[64 + lane]  = a1 / de1 + bias[64 + lane];
  op[128 + lane] = a2 / de2 + bias[128 + lane];
  op[192 + lane] = a3 / de3 + bias[192 + lane];
}

// in-place exact GELU + per-column sum/sumsq partials
__global__ void gelu_stats_k(float* __restrict__ x, float* __restrict__ sum,
                             float* __restrict__ sumsq, int rows_per_block) {
  int f = threadIdx.x;
  int r0 = blockIdx.x * rows_per_block;
  float s = 0.f, sq = 0.f;
  for (int r = r0; r < r0 + rows_per_block; ++r) {
    float v = x[(size_t)r * FDIM + f];
    float g = 0.5f * v * (1.0f + erff(v * 0.7071067811865476f));
    x[(size_t)r * FDIM + f] = g;
    s += g;
    sq += g * g;
  }
  atomicAdd(&sum[f], s);
  atomicAdd(&sumsq[f], sq);
}

__global__ void bn_finalize_k(const float* __restrict__ sum, const float* __restrict__ sumsq,
                              const float* __restrict__ g, const float* __restrict__ be,
                              float* __restrict__ scale, float* __restrict__ shift, float inv_n) {
  int f = threadIdx.x;
  float mean = sum[f] * inv_n;
  float var = sumsq[f] * inv_n - mean * mean;
  float sc = g[f] / sqrtf(var + BN_EPS);
  scale[f] = sc;
  shift[f] = be[f] - mean * sc;
}

// fused: x = x*scale+shift (in place) and score = (x.w)/||w||, one wave per node
__global__ void bn_score_k(float* __restrict__ x, const float* __restrict__ scale,
                           const float* __restrict__ shift, const float* __restrict__ w,
                           float* __restrict__ score, int n) {
  int gid = blockIdx.x * blockDim.x + threadIdx.x;
  int node = gid >> 6, lane = threadIdx.x & 63;
  if (node >= n) return;
  float* xp = x + (size_t)node * FDIM;
  float p = 0.f, nw = 0.f;
#pragma unroll
  for (int j = 0; j < 4; ++j) {
    int c = j * 64 + lane;
    float v = fmaf(xp[c], scale[c], shift[c]);
    xp[c] = v;
    float wv = w[c];
    p = fmaf(v, wv, p);
    nw = fmaf(wv, wv, nw);
  }
#pragma unroll
  for (int off = 32; off > 0; off >>= 1) {
    p += __shfl_xor(p, off);
    nw += __shfl_xor(nw, off);
  }
  if (lane == 0) score[node] = p / sqrtf(nw);
}

// per-graph bitonic sort descending (tie: lower index first); keep first KEEP
template <int NPG_T, int KEEP>
__global__ void topk_k(const float* __restrict__ score, float* __restrict__ vals,
                       int* __restrict__ gidx, int* __restrict__ inv) {
  __shared__ float sv[NPG_T];
  __shared__ int si[NPG_T];
  int tid = threadIdx.x, b = blockIdx.x;
  sv[tid] = score[b * NPG_T + tid];
  si[tid] = tid;
  for (int k = 2; k <= NPG_T; k <<= 1) {
    for (int j = k >> 1; j > 0; j >>= 1) {
      __syncthreads();
      int ixj = tid ^ j;
      if (ixj > tid) {
        float v1 = sv[tid], v2 = sv[ixj];
        int i1 = si[tid], i2 = si[ixj];
        bool before = (v1 > v2) || (v1 == v2 && i1 < i2);
        bool up = ((tid & k) == 0);
        if (up ? !before : before) {
          sv[tid] = v2; sv[ixj] = v1;
          si[tid] = i2; si[ixj] = i1;
        }
      }
    }
  }
  __syncthreads();
  if (tid < KEEP) {
    int gid = b * NPG_T + si[tid];
    int r = b * KEEP + tid;
    vals[r] = sv[tid];
    gidx[r] = gid;
    if (inv) inv[gid] = r;
  }
}

__global__ void gather_scale_k(const float* __restrict__ x, const int* __restrict__ gidx,
                               const float* __restrict__ vals, float* __restrict__ xn) {
  int r = blockIdx.x, f = threadIdx.x;
  float t = tanhf(vals[r]);
  xn[(size_t)r * FDIM + f] = x[(size_t)gidx[r] * FDIM + f] * t;
}

#define RD_ROWS 16
__global__ void readout_part_k(const float* __restrict__ xn, float* __restrict__ pmax,
                               float* __restrict__ psum, int kk, int seg_per_graph) {
  int blk = blockIdx.x, f = threadIdx.x;
  int b = blk / seg_per_graph, s = blk - b * seg_per_graph;
  const float* p = xn + ((size_t)b * kk + (size_t)s * RD_ROWS) * FDIM + f;
  float mx = -3.0e38f, sm = 0.f;
#pragma unroll
  for (int j = 0; j < RD_ROWS; ++j) {
    float v = p[(size_t)j * FDIM];
    mx = fmaxf(mx, v);
    sm += v;
  }
  pmax[(size_t)blk * FDIM + f] = mx;
  psum[(size_t)blk * FDIM + f] = sm;
}

__global__ void readout_final_k(const float* __restrict__ pmax, const float* __restrict__ psum,
                                float* __restrict__ xr, int seg_per_graph, float inv_k) {
  int b = blockIdx.x, f = threadIdx.x;
  float mx = -3.0e38f, sm = 0.f;
  for (int s = 0; s < seg_per_graph; ++s) {
    mx = fmaxf(mx, pmax[((size_t)b * seg_per_graph + s) * FDIM + f]);
    sm += psum[((size_t)b * seg_per_graph + s) * FDIM + f];
  }
  xr[b * (2 * FDIM) + f] = mx;
  xr[b * (2 * FDIM) + FDIM + f] = sm * inv_k;
}

// fused remap + degree count for layer-2 CSR
__global__ void remap_deg_k(const int* __restrict__ src, const int* __restrict__ dst,
                            const int* __restrict__ inv, int* __restrict__ ns,
                            int* __restrict__ nd, int* __restrict__ deg, int ne) {
  int e = blockIdx.x * blockDim.x + threadIdx.x;
  if (e < ne) {
    int a = inv[src[e]], bb = inv[dst[e]];
    bool ok = (a >= 0) && (bb >= 0);
    ns[e] = ok ? a : -1;
    nd[e] = ok ? bb : -1;
    if (ok) atomicAdd(&deg[bb], 1);
  }
}

__global__ void final_k(const float* __restrict__ x1, const float* __restrict__ x2,
                        const float* __restrict__ Wl, const float* __restrict__ bl,
                        float* __restrict__ out) {
  __shared__ float xs[2 * FDIM];
  int b = blockIdx.x, o = threadIdx.x;
  xs[o] = x1[b * 512 + o] + x2[b * 512 + o];
  xs[o + 256] = x1[b * 512 + 256 + o] + x2[b * 512 + 256 + o];
  __syncthreads();
  float acc = bl[o];
  const float* wp = Wl + (size_t)o * 512;
  for (int j = 0; j < 512; ++j) acc = fmaf(xs[j], wp[j], acc);
  out[b * OUT_DIM + o] = acc;
}

extern "C" void kernel_launch(void* const* d_in, const int* in_sizes, int n_in,
                              void* d_out, int out_size, void* d_ws, size_t ws_size,
                              hipStream_t stream) {
  (void)in_sizes; (void)n_in; (void)out_size; (void)ws_size;
  const float* x   = (const float*)d_in[0];
  const int* eidx  = (const int*)d_in[1];
  const int* src   = eidx;
  const int* dst   = eidx + NE;
  const float* W1  = (const float*)d_in[3];
  const float* as1 = (const float*)d_in[4];
  const float* ad1 = (const float*)d_in[5];
  const float* b1  = (const float*)d_in[6];
  const float* g1  = (const float*)d_in[7];
  const float* be1 = (const float*)d_in[8];
  const float* pw1 = (const float*)d_in[9];
  const float* W2  = (const float*)d_in[10];
  const float* as2 = (const float*)d_in[11];
  const float* ad2 = (const float*)d_in[12];
  const float* b2  = (const float*)d_in[13];
  const float* g2  = (const float*)d_in[14];
  const float* be2 = (const float*)d_in[15];
  const float* pw2 = (const float*)d_in[16];
  const float* Wl  = (const float*)d_in[17];
  const float* bl  = (const float*)d_in[18];
  float* out = (float*)d_out;

  char* wsp = (char*)d_ws;
  size_t off = 0;
  auto alloc = [&](size_t bytes) -> void* {
    void* p = wsp + off;
    off += (bytes + 255) & ~(size_t)255;
    return p;
  };
  float* h1    = (float*)alloc((size_t)NN1 * FDIM * 4);  // reused as h2
  float* out1  = (float*)alloc((size_t)NN1 * FDIM * 4);  // reused as out2
  float* xn1   = (float*)alloc((size_t)NN2 * FDIM * 4);  // reused as xn2
  float* asn   = (float*)alloc((size_t)NN1 * NHEADS * 4);
  float* adn   = (float*)alloc((size_t)NN1 * NHEADS * 4);
  float4* pexp = (float4*)alloc((size_t)NE * 16);
  int*   deg   = (int*)alloc((size_t)NN1 * 4);
  int*   rowst = (int*)alloc((size_t)(NN1 + 1) * 4);
  int*   cursor= (int*)alloc((size_t)NN1 * 4);
  int*   scanv = (int*)alloc((size_t)NN1 * 4);
  int*   bsum  = (int*)alloc(64 * 4);
  int*   csrc  = (int*)alloc((size_t)NE * 4);
  int*   ns    = (int*)alloc((size_t)NE * 4);
  int*   nd    = (int*)alloc((size_t)NE * 4);
  int*   inv1  = (int*)alloc((size_t)NN1 * 4);
  float* score = (float*)alloc((size_t)NN1 * 4);
  float* vals  = (float*)alloc((size_t)NN2 * 4);
  int*   gidx  = (int*)alloc((size_t)NN2 * 4);
  float* x1r   = (float*)alloc((size_t)NB * 512 * 4);
  float* x2r   = (float*)alloc((size_t)NB * 512 * 4);
  float* bnsum = (float*)alloc(FDIM * 4);   // bnsq adjacent: single memset
  float* bnsq  = (float*)alloc(FDIM * 4);
  float* bnsc  = (float*)alloc(FDIM * 4);
  float* bnsh  = (float*)alloc(FDIM * 4);
  float* pmax  = (float*)alloc((size_t)(NN2 / RD_ROWS) * FDIM * 4);
  float* psum  = (float*)alloc((size_t)(NN2 / RD_ROWS) * FDIM * 4);

  // ---------- layer 1 ----------
  gemm128_f32<<<dim3(FDIM / 128, NN1 / 128), 256, 0, stream>>>(x, W1, h1, NN1, FDIM, IN_DIM);
  attn_coef_k<<<NN1 / 4, 256, 0, stream>>>(h1, as1, ad1, asn, adn, NN1);
  hipMemsetAsync(deg, 0, (size_t)NN1 * 4, stream);
  deg_count_k<<<NE / 256, 256, 0, stream>>>(dst, deg, NE);
  exscan1_k<<<NN1 / 1024, 1024, 0, stream>>>(deg, scanv, bsum);
  exscan2_k<<<NN1 / 1024, 1024, 0, stream>>>(scanv, bsum, rowst, cursor, NN1 / 1024, NN1);
  csr_fill_p_k<<<NE / 256, 256, 0, stream>>>(src, dst, cursor, (const float4*)asn,
                                             (const float4*)adn, csrc, pexp, NE);
  gat_agg_k<<<NN1 / 4, 256, 0, stream>>>(h1, (const float4*)asn, (const float4*)adn,
                                         rowst, csrc, pexp, b1, out1, NN1);
  hipMemsetAsync(bnsum, 0, FDIM * 2 * 4, stream);
  gelu_stats_k<<<NN1 / 128, 256, 0, stream>>>(out1, bnsum, bnsq, 128);
  bn_finalize_k<<<1, 256, 0, stream>>>(bnsum, bnsq, g1, be1, bnsc, bnsh, 1.0f / NN1);
  bn_score_k<<<NN1 / 4, 256, 0, stream>>>(out1, bnsc, bnsh, pw1, score, NN1);
  // ---------- pool 1 ----------
  hipMemsetAsync(inv1, 0xFF, (size_t)NN1 * 4, stream);
  topk_k<1024, 512><<<NB, 1024, 0, stream>>>(score, vals, gidx, inv1);
  gather_scale_k<<<NN2, 256, 0, stream>>>(out1, gidx, vals, xn1);
  readout_part_k<<<NN2 / RD_ROWS, 256, 0, stream>>>(xn1, pmax, psum, KK1, KK1 / RD_ROWS);
  readout_final_k<<<NB, 256, 0, stream>>>(pmax, psum, x1r, KK1 / RD_ROWS, 1.0f / KK1);
  hipMemsetAsync(deg, 0, (size_t)NN2 * 4, stream);
  remap_deg_k<<<NE / 256, 256, 0, stream>>>(src, dst, inv1, ns, nd, deg, NE);
  // ---------- layer 2 ----------
  float* h2 = h1;
  float* out2 = out1;
  gemm128_f32<<<dim3(FDIM / 128, NN2 / 128), 256, 0, stream>>>(xn1, W2, h2, NN2, FDIM, FDIM);
  attn_coef_k<<<NN2 / 4, 256, 0, stream>>>(h2, as2, ad2, asn, adn, NN2);
  exscan1_k<<<NN2 / 1024, 1024, 0, stream>>>(deg, scanv, bsum);
  exscan2_k<<<NN2 / 1024, 1024, 0, stream>>>(scanv, bsum, rowst, cursor, NN2 / 1024, NN2);
  csr_fill_p_k<<<NE / 256, 256, 0, stream>>>(ns, nd, cursor, (const float4*)asn,
                                             (const float4*)adn, csrc, pexp, NE);
  gat_agg_k<<<NN2 / 4, 256, 0, stream>>>(h2, (const float4*)asn, (const float4*)adn,
                                         rowst, csrc, pexp, b2, out2, NN2);
  hipMemsetAsync(bnsum, 0, FDIM * 2 * 4, stream);
  gelu_stats_k<<<NN2 / 128, 256, 0, stream>>>(out2, bnsum, bnsq, 128);
  bn_finalize_k<<<1, 256, 0, stream>>>(bnsum, bnsq, g2, be2, bnsc, bnsh, 1.0f / NN2);
  bn_score_k<<<NN2 / 4, 256, 0, stream>>>(out2, bnsc, bnsh, pw2, score, NN2);
  // ---------- pool 2 ----------
  topk_k<512, 256><<<NB, 512, 0, stream>>>(score, vals, gidx, nullptr);
  float* xn2 = xn1;
  gather_scale_k<<<NN3, 256, 0, stream>>>(out2, gidx, vals, xn2);
  readout_part_k<<<NN3 / RD_ROWS, 256, 0, stream>>>(xn2, pmax, psum, KK2, KK2 / RD_ROWS);
  readout_final_k<<<NB, 256, 0, stream>>>(pmax, psum, x2r, KK2 / RD_ROWS, 1.0f / KK2);
  // ---------- final ----------
  final_k<<<NB, 256, 0, stream>>>(x1r, x2r, Wl, bl, out);
}

// Round 4
// 426.565 us; speedup vs baseline: 1.8224x; 1.1909x over previous
//
#include <hip/hip_runtime.h>

#define NN1 32768
#define NE  262144
#define FDIM 256
#define NHEADS 4
#define HIDC 64
#define IN_DIM 128
#define NB 32
#define KK1 512
#define NN2 16384   // NB*KK1
#define KK2 256
#define NN3 8192    // NB*KK2
#define OUT_DIM 256
#define BN_EPS 1e-5f
#define NEG_SLOPE 0.2f

typedef _Float16 half8 __attribute__((ext_vector_type(8)));
typedef _Float16 half4v __attribute__((ext_vector_type(4)));
typedef float floatx4 __attribute__((ext_vector_type(4)));

__device__ __forceinline__ float lrelu(float x) { return x >= 0.f ? x : NEG_SLOPE * x; }
__device__ __forceinline__ float gelu(float v) {
  return 0.5f * v * (1.0f + erff(v * 0.7071067811865476f));
}

// fp32 -> fp16, 4 elements/thread
__global__ void f32_to_f16_k(const float4* __restrict__ in, half4v* __restrict__ out, int n4) {
  int i = blockIdx.x * blockDim.x + threadIdx.x;
  if (i >= n4) return;
  float4 v = in[i];
  half4v h;
  h[0] = (_Float16)v.x; h[1] = (_Float16)v.y; h[2] = (_Float16)v.z; h[3] = (_Float16)v.w;
  out[i] = h;
}

// B[K][N] fp32 -> BT[N][K] fp16 (small weight matrices)
__global__ void convT_k(const float* __restrict__ B, _Float16* __restrict__ BT,
                        int K, int logK, int N) {
  int idx = blockIdx.x * blockDim.x + threadIdx.x;
  int n = idx >> logK, k = idx & (K - 1);
  BT[idx] = (_Float16)B[k * N + n];
}

// ---------------- MFMA fp16 GEMM: C[M,N] = A[M,K] * BT[N,K]^T
// block tile 64(M) x 128(N), BK=32, 4 waves in 2x2, wave tile 32x64
template <int K>
__global__ void gemm_f16(const _Float16* __restrict__ A, const _Float16* __restrict__ BT,
                         float* __restrict__ C, int N) {
  __shared__ _Float16 As[64 * 40];   // stride 40 halves: <=2-way bank alias
  __shared__ _Float16 Bs[128 * 40];
  int tid = threadIdx.x;
  int lane = tid & 63, w = tid >> 6;
  int bm = blockIdx.y * 64, bn = blockIdx.x * 128;
  int wm = (w & 1) * 32, wn = (w >> 1) * 64;
  floatx4 acc[2][4] = {};
  int ar = tid >> 2, ac = (tid & 3) * 8;   // A staging: 64 rows x 32 halves
  int br = tid >> 1, bc = (tid & 1) * 16;  // B staging: 128 rows x 32 halves
  int fm = lane & 15, fq = (lane >> 4) * 8;
  for (int k0 = 0; k0 < K; k0 += 32) {
    __syncthreads();
    *(half8*)&As[ar * 40 + ac] = *(const half8*)&A[(size_t)(bm + ar) * K + k0 + ac];
    *(half8*)&Bs[br * 40 + bc] = *(const half8*)&BT[(size_t)(bn + br) * K + k0 + bc];
    *(half8*)&Bs[br * 40 + bc + 8] = *(const half8*)&BT[(size_t)(bn + br) * K + k0 + bc + 8];
    __syncthreads();
    half8 af[2], bf[4];
#pragma unroll
    for (int mt = 0; mt < 2; ++mt)
      af[mt] = *(const half8*)&As[(wm + mt * 16 + fm) * 40 + fq];
#pragma unroll
    for (int nt = 0; nt < 4; ++nt)
      bf[nt] = *(const half8*)&Bs[(wn + nt * 16 + fm) * 40 + fq];
#pragma unroll
    for (int mt = 0; mt < 2; ++mt)
#pragma unroll
      for (int nt = 0; nt < 4; ++nt)
        acc[mt][nt] = __builtin_amdgcn_mfma_f32_16x16x32_f16(af[mt], bf[nt], acc[mt][nt], 0, 0, 0);
  }
  // C/D layout: col = lane&15, row = (lane>>4)*4 + reg   [m89/m91-verified]
  int row0 = bm + wm + (lane >> 4) * 4;
  int col0 = bn + wn + (lane & 15);
#pragma unroll
  for (int mt = 0; mt < 2; ++mt)
#pragma unroll
    for (int nt = 0; nt < 4; ++nt) {
      float* cp = C + (size_t)(row0 + mt * 16) * N + col0 + nt * 16;
#pragma unroll
      for (int i = 0; i < 4; ++i) cp[(size_t)i * N] = acc[mt][nt][i];
    }
}

// per-node attention coefficients
__global__ void attn_coef_k(const float* __restrict__ h, const float* __restrict__ a_s,
                            const float* __restrict__ a_d, float* __restrict__ asn,
                            float* __restrict__ adn, int n) {
  int gid = blockIdx.x * blockDim.x + threadIdx.x;
  int node = gid >> 6, lane = threadIdx.x & 63;
  if (node >= n) return;
  const float* hp = h + (size_t)node * FDIM;
  float ps[NHEADS], pd[NHEADS];
#pragma unroll
  for (int hh = 0; hh < NHEADS; ++hh) {
    float hv = hp[hh * HIDC + lane];
    ps[hh] = hv * a_s[hh * HIDC + lane];
    pd[hh] = hv * a_d[hh * HIDC + lane];
  }
#pragma unroll
  for (int off = 32; off > 0; off >>= 1) {
#pragma unroll
    for (int hh = 0; hh < NHEADS; ++hh) {
      ps[hh] += __shfl_xor(ps[hh], off);
      pd[hh] += __shfl_xor(pd[hh], off);
    }
  }
  if (lane == 0) {
#pragma unroll
    for (int hh = 0; hh < NHEADS; ++hh) {
      asn[node * NHEADS + hh] = ps[hh];
      adn[node * NHEADS + hh] = pd[hh];
    }
  }
}

__global__ void deg_count_k(const int* __restrict__ dst, int* __restrict__ deg, int ne) {
  int e = blockIdx.x * blockDim.x + threadIdx.x;
  if (e < ne) {
    int d = dst[e];
    if (d >= 0) atomicAdd(&deg[d], 1);
  }
}

// 2-level exclusive scan
__global__ void exscan1_k(const int* __restrict__ in, int* __restrict__ outv,
                          int* __restrict__ bsum) {
  __shared__ int wsum[16];
  int tid = threadIdx.x, lane = tid & 63, wv = tid >> 6;
  int base = blockIdx.x * 1024;
  int v = in[base + tid];
  int x = v;
#pragma unroll
  for (int off = 1; off < 64; off <<= 1) {
    int t = __shfl_up(x, off);
    if (lane >= off) x += t;
  }
  if (lane == 63) wsum[wv] = x;
  __syncthreads();
  int woff = 0;
  for (int i = 0; i < wv; i++) woff += wsum[i];
  outv[base + tid] = woff + x - v;
  if (tid == 1023) bsum[blockIdx.x] = woff + x;
}

__global__ void exscan2_k(const int* __restrict__ outv, const int* __restrict__ bsum,
                          int* __restrict__ rowstart, int* __restrict__ cursor,
                          int nblocks, int n) {
  __shared__ int goff;
  int b = blockIdx.x, tid = threadIdx.x;
  if (tid == 0) {
    int s = 0;
    for (int i = 0; i < b; i++) s += bsum[i];
    goff = s;
    if (b == nblocks - 1) rowstart[n] = s + bsum[b];
  }
  __syncthreads();
  int val = outv[b * 1024 + tid] + goff;
  rowstart[b * 1024 + tid] = val;
  cursor[b * 1024 + tid] = val;
}

// CSR fill + per-edge softmax numerator exp(lrelu(asn[s]+adn[d])) (shift-free softmax)
__global__ void csr_fill_p_k(const int* __restrict__ src, const int* __restrict__ dst,
                             int* __restrict__ cursor, const float4* __restrict__ asn4,
                             const float4* __restrict__ adn4, int* __restrict__ csrc,
                             float4* __restrict__ pexp, int ne) {
  int e = blockIdx.x * blockDim.x + threadIdx.x;
  if (e >= ne) return;
  int d = dst[e];
  if (d < 0) return;
  int s = src[e];
  int pos = atomicAdd(&cursor[d], 1);
  csrc[pos] = s;
  float4 a = asn4[s], b = adn4[d];
  float4 p;
  p.x = expf(lrelu(a.x + b.x));
  p.y = expf(lrelu(a.y + b.y));
  p.z = expf(lrelu(a.z + b.z));
  p.w = expf(lrelu(a.w + b.w));
  pexp[pos] = p;
}

// one wave per dst node, single pass; epilogue applies exact GELU
__global__ void gat_agg_k(const float* __restrict__ h, const float4* __restrict__ asn4,
                          const float4* __restrict__ adn4, const int* __restrict__ rowstart,
                          const int* __restrict__ csrc, const float4* __restrict__ pexp,
                          const float* __restrict__ bias, float* __restrict__ out, int n) {
  int lane = threadIdx.x & 63;
  int d = __builtin_amdgcn_readfirstlane(blockIdx.x * 4 + (threadIdx.x >> 6));
  if (d >= n) return;
  int beg = rowstart[d], end = rowstart[d + 1];
  float4 sa = asn4[d], sb = adn4[d];
  float p0 = expf(lrelu(sa.x + sb.x));
  float p1 = expf(lrelu(sa.y + sb.y));
  float p2 = expf(lrelu(sa.z + sb.z));
  float p3 = expf(lrelu(sa.w + sb.w));
  const float* hp = h + (size_t)d * FDIM;
  float de0 = p0, de1 = p1, de2 = p2, de3 = p3;
  float a0 = p0 * hp[lane];
  float a1 = p1 * hp[64 + lane];
  float a2 = p2 * hp[128 + lane];
  float a3 = p3 * hp[192 + lane];
  for (int e = beg; e < end; ++e) {
    int s = csrc[e];
    float4 p = pexp[e];
    const float* hs = h + (size_t)s * FDIM;
    de0 += p.x; de1 += p.y; de2 += p.z; de3 += p.w;
    a0 = fmaf(p.x, hs[lane], a0);
    a1 = fmaf(p.y, hs[64 + lane], a1);
    a2 = fmaf(p.z, hs[128 + lane], a2);
    a3 = fmaf(p.w, hs[192 + lane], a3);
  }
  float* op = out + (size_t)d * FDIM;
  op[lane]       = gelu(a0 / de0 + bias[lane]);
  op[64 + lane]  = gelu(a1 / de1 + bias[64 + lane]);
  op[128 + lane] = gelu(a2 / de2 + bias[128 + lane]);
  op[192 + lane] = gelu(a3 / de3 + bias[192 + lane]);
}

// per-column sum/sumsq partials (read-only; GELU already applied)
__global__ void stats_k(const float* __restrict__ x, float* __restrict__ sum,
                        float* __restrict__ sumsq, int rows_per_block) {
  int f = threadIdx.x;
  int r0 = blockIdx.x * rows_per_block;
  float s = 0.f, sq = 0.f;
  for (int r = r0; r < r0 + rows_per_block; ++r) {
    float g = x[(size_t)r * FDIM + f];
    s += g;
    sq += g * g;
  }
  atomicAdd(&sum[f], s);
  atomicAdd(&sumsq[f], sq);
}

__global__ void bn_finalize_k(const float* __restrict__ sum, const float* __restrict__ sumsq,
                              const float* __restrict__ g, const float* __restrict__ be,
                              float* __restrict__ scale, float* __restrict__ shift, float inv_n) {
  int f = threadIdx.x;
  float mean = sum[f] * inv_n;
  float var = sumsq[f] * inv_n - mean * mean;
  float sc = g[f] / sqrtf(var + BN_EPS);
  scale[f] = sc;
  shift[f] = be[f] - mean * sc;
}

// fused: x = x*scale+shift (in place) and score = (x.w)/||w||
__global__ void bn_score_k(float* __restrict__ x, const float* __restrict__ scale,
                           const float* __restrict__ shift, const float* __restrict__ w,
                           float* __restrict__ score, int n) {
  int gid = blockIdx.x * blockDim.x + threadIdx.x;
  int node = gid >> 6, lane = threadIdx.x & 63;
  if (node >= n) return;
  float* xp = x + (size_t)node * FDIM;
  float p = 0.f, nw = 0.f;
#pragma unroll
  for (int j = 0; j < 4; ++j) {
    int c = j * 64 + lane;
    float v = fmaf(xp[c], scale[c], shift[c]);
    xp[c] = v;
    float wv = w[c];
    p = fmaf(v, wv, p);
    nw = fmaf(wv, wv, nw);
  }
#pragma unroll
  for (int off = 32; off > 0; off >>= 1) {
    p += __shfl_xor(p, off);
    nw += __shfl_xor(nw, off);
  }
  if (lane == 0) score[node] = p / sqrtf(nw);
}

// per-graph bitonic sort descending (tie: lower index first); keep first KEEP
template <int NPG_T, int KEEP>
__global__ void topk_k(const float* __restrict__ score, float* __restrict__ vals,
                       int* __restrict__ gidx, int* __restrict__ inv) {
  __shared__ float sv[NPG_T];
  __shared__ int si[NPG_T];
  int tid = threadIdx.x, b = blockIdx.x;
  sv[tid] = score[b * NPG_T + tid];
  si[tid] = tid;
  for (int k = 2; k <= NPG_T; k <<= 1) {
    for (int j = k >> 1; j > 0; j >>= 1) {
      __syncthreads();
      int ixj = tid ^ j;
      if (ixj > tid) {
        float v1 = sv[tid], v2 = sv[ixj];
        int i1 = si[tid], i2 = si[ixj];
        bool before = (v1 > v2) || (v1 == v2 && i1 < i2);
        bool up = ((tid & k) == 0);
        if (up ? !before : before) {
          sv[tid] = v2; sv[ixj] = v1;
          si[tid] = i2; si[ixj] = i1;
        }
      }
    }
  }
  __syncthreads();
  if (tid < KEEP) {
    int gid = b * NPG_T + si[tid];
    int r = b * KEEP + tid;
    vals[r] = sv[tid];
    gidx[r] = gid;
    if (inv) inv[gid] = r;
  }
}

// gather + tanh scale; also emits fp16 copy (A-operand of next GEMM)
__global__ void gather_scale_k(const float* __restrict__ x, const int* __restrict__ gidx,
                               const float* __restrict__ vals, float* __restrict__ xn,
                               _Float16* __restrict__ xh) {
  int r = blockIdx.x, f = threadIdx.x;
  float t = tanhf(vals[r]);
  float v = x[(size_t)gidx[r] * FDIM + f] * t;
  xn[(size_t)r * FDIM + f] = v;
  if (xh) xh[(size_t)r * FDIM + f] = (_Float16)v;
}

#define RD_ROWS 16
__global__ void readout_part_k(const float* __restrict__ xn, float* __restrict__ pmax,
                               float* __restrict__ psum, int kk, int seg_per_graph) {
  int blk = blockIdx.x, f = threadIdx.x;
  int b = blk / seg_per_graph, s = blk - b * seg_per_graph;
  const float* p = xn + ((size_t)b * kk + (size_t)s * RD_ROWS) * FDIM + f;
  float mx = -3.0e38f, sm = 0.f;
#pragma unroll
  for (int j = 0; j < RD_ROWS; ++j) {
    float v = p[(size_t)j * FDIM];
    mx = fmaxf(mx, v);
    sm += v;
  }
  pmax[(size_t)blk * FDIM + f] = mx;
  psum[(size_t)blk * FDIM + f] = sm;
}

__global__ void readout_final_k(const float* __restrict__ pmax, const float* __restrict__ psum,
                                float* __restrict__ xr, int seg_per_graph, float inv_k) {
  int b = blockIdx.x, f = threadIdx.x;
  float mx = -3.0e38f, sm = 0.f;
  for (int s = 0; s < seg_per_graph; ++s) {
    mx = fmaxf(mx, pmax[((size_t)b * seg_per_graph + s) * FDIM + f]);
    sm += psum[((size_t)b * seg_per_graph + s) * FDIM + f];
  }
  xr[b * (2 * FDIM) + f] = mx;
  xr[b * (2 * FDIM) + FDIM + f] = sm * inv_k;
}

// fused remap + degree count for layer-2 CSR
__global__ void remap_deg_k(const int* __restrict__ src, const int* __restrict__ dst,
                            const int* __restrict__ inv, int* __restrict__ ns,
                            int* __restrict__ nd, int* __restrict__ deg, int ne) {
  int e = blockIdx.x * blockDim.x + threadIdx.x;
  if (e < ne) {
    int a = inv[src[e]], bb = inv[dst[e]];
    bool ok = (a >= 0) && (bb >= 0);
    ns[e] = ok ? a : -1;
    nd[e] = ok ? bb : -1;
    if (ok) atomicAdd(&deg[bb], 1);
  }
}

__global__ void final_k(const float* __restrict__ x1, const float* __restrict__ x2,
                        const float* __restrict__ Wl, const float* __restrict__ bl,
                        float* __restrict__ out) {
  __shared__ float xs[2 * FDIM];
  int b = blockIdx.x, o = threadIdx.x;
  xs[o] = x1[b * 512 + o] + x2[b * 512 + o];
  xs[o + 256] = x1[b * 512 + 256 + o] + x2[b * 512 + 256 + o];
  __syncthreads();
  float acc = bl[o];
  const float* wp = Wl + (size_t)o * 512;
  for (int j = 0; j < 512; ++j) acc = fmaf(xs[j], wp[j], acc);
  out[b * OUT_DIM + o] = acc;
}

extern "C" void kernel_launch(void* const* d_in, const int* in_sizes, int n_in,
                              void* d_out, int out_size, void* d_ws, size_t ws_size,
                              hipStream_t stream) {
  (void)in_sizes; (void)n_in; (void)out_size; (void)ws_size;
  const float* x   = (const float*)d_in[0];
  const int* eidx  = (const int*)d_in[1];
  const int* src   = eidx;
  const int* dst   = eidx + NE;
  const float* W1  = (const float*)d_in[3];
  const float* as1 = (const float*)d_in[4];
  const float* ad1 = (const float*)d_in[5];
  const float* b1  = (const float*)d_in[6];
  const float* g1  = (const float*)d_in[7];
  const float* be1 = (const float*)d_in[8];
  const float* pw1 = (const float*)d_in[9];
  const float* W2  = (const float*)d_in[10];
  const float* as2 = (const float*)d_in[11];
  const float* ad2 = (const float*)d_in[12];
  const float* b2  = (const float*)d_in[13];
  const float* g2  = (const float*)d_in[14];
  const float* be2 = (const float*)d_in[15];
  const float* pw2 = (const float*)d_in[16];
  const float* Wl  = (const float*)d_in[17];
  const float* bl  = (const float*)d_in[18];
  float* out = (float*)d_out;

  char* wsp = (char*)d_ws;
  size_t off = 0;
  auto alloc = [&](size_t bytes) -> void* {
    void* p = wsp + off;
    off += (bytes + 255) & ~(size_t)255;
    return p;
  };
  float* h1    = (float*)alloc((size_t)NN1 * FDIM * 4);  // reused as h2
  float* out1  = (float*)alloc((size_t)NN1 * FDIM * 4);  // reused as out2
  float* xn1   = (float*)alloc((size_t)NN2 * FDIM * 4);  // reused as xn2
  _Float16* ah = (_Float16*)alloc((size_t)NN1 * IN_DIM * 2);  // fp16 A (both layers)
  _Float16* bt = (_Float16*)alloc((size_t)FDIM * FDIM * 2);   // fp16 B^T
  float* asn   = (float*)alloc((size_t)NN1 * NHEADS * 4);
  float* adn   = (float*)alloc((size_t)NN1 * NHEADS * 4);
  float4* pexp = (float4*)alloc((size_t)NE * 16);
  int*   deg   = (int*)alloc((size_t)NN1 * 4);
  int*   rowst = (int*)alloc((size_t)(NN1 + 1) * 4);
  int*   cursor= (int*)alloc((size_t)NN1 * 4);
  int*   scanv = (int*)alloc((size_t)NN1 * 4);
  int*   bsum  = (int*)alloc(64 * 4);
  int*   csrc  = (int*)alloc((size_t)NE * 4);
  int*   ns    = (int*)alloc((size_t)NE * 4);
  int*   nd    = (int*)alloc((size_t)NE * 4);
  int*   inv1  = (int*)alloc((size_t)NN1 * 4);
  float* score = (float*)alloc((size_t)NN1 * 4);
  float* vals  = (float*)alloc((size_t)NN2 * 4);
  int*   gidx  = (int*)alloc((size_t)NN2 * 4);
  float* x1r   = (float*)alloc((size_t)NB * 512 * 4);
  float* x2r   = (float*)alloc((size_t)NB * 512 * 4);
  float* bnsum = (float*)alloc(FDIM * 4);   // bnsq adjacent: single memset
  float* bnsq  = (float*)alloc(FDIM * 4);
  float* bnsc  = (float*)alloc(FDIM * 4);
  float* bnsh  = (float*)alloc(FDIM * 4);
  float* pmax  = (float*)alloc((size_t)(NN2 / RD_ROWS) * FDIM * 4);
  float* psum  = (float*)alloc((size_t)(NN2 / RD_ROWS) * FDIM * 4);

  // ---------- layer 1 ----------
  f32_to_f16_k<<<(NN1 * IN_DIM / 4) / 256, 256, 0, stream>>>((const float4*)x, (half4v*)ah,
                                                             NN1 * IN_DIM / 4);
  convT_k<<<(FDIM * IN_DIM) / 256, 256, 0, stream>>>(W1, bt, IN_DIM, 7, FDIM);
  gemm_f16<IN_DIM><<<dim3(FDIM / 128, NN1 / 64), 256, 0, stream>>>(ah, bt, h1, FDIM);
  attn_coef_k<<<NN1 / 4, 256, 0, stream>>>(h1, as1, ad1, asn, adn, NN1);
  hipMemsetAsync(deg, 0, (size_t)NN1 * 4, stream);
  deg_count_k<<<NE / 256, 256, 0, stream>>>(dst, deg, NE);
  exscan1_k<<<NN1 / 1024, 1024, 0, stream>>>(deg, scanv, bsum);
  exscan2_k<<<NN1 / 1024, 1024, 0, stream>>>(scanv, bsum, rowst, cursor, NN1 / 1024, NN1);
  csr_fill_p_k<<<NE / 256, 256, 0, stream>>>(src, dst, cursor, (const float4*)asn,
                                             (const float4*)adn, csrc, pexp, NE);
  gat_agg_k<<<NN1 / 4, 256, 0, stream>>>(h1, (const float4*)asn, (const float4*)adn,
                                         rowst, csrc, pexp, b1, out1, NN1);
  hipMemsetAsync(bnsum, 0, FDIM * 2 * 4, stream);
  stats_k<<<NN1 / 128, 256, 0, stream>>>(out1, bnsum, bnsq, 128);
  bn_finalize_k<<<1, 256, 0, stream>>>(bnsum, bnsq, g1, be1, bnsc, bnsh, 1.0f / NN1);
  bn_score_k<<<NN1 / 4, 256, 0, stream>>>(out1, bnsc, bnsh, pw1, score, NN1);
  // ---------- pool 1 ----------
  hipMemsetAsync(inv1, 0xFF, (size_t)NN1 * 4, stream);
  topk_k<1024, 512><<<NB, 1024, 0, stream>>>(score, vals, gidx, inv1);
  gather_scale_k<<<NN2, 256, 0, stream>>>(out1, gidx, vals, xn1, ah);
  readout_part_k<<<NN2 / RD_ROWS, 256, 0, stream>>>(xn1, pmax, psum, KK1, KK1 / RD_ROWS);
  readout_final_k<<<NB, 256, 0, stream>>>(pmax, psum, x1r, KK1 / RD_ROWS, 1.0f / KK1);
  hipMemsetAsync(deg, 0, (size_t)NN2 * 4, stream);
  remap_deg_k<<<NE / 256, 256, 0, stream>>>(src, dst, inv1, ns, nd, deg, NE);
  // ---------- layer 2 ----------
  float* h2 = h1;
  float* out2 = out1;
  convT_k<<<(FDIM * FDIM) / 256, 256, 0, stream>>>(W2, bt, FDIM, 8, FDIM);
  gemm_f16<FDIM><<<dim3(FDIM / 128, NN2 / 64), 256, 0, stream>>>(ah, bt, h2, FDIM);
  attn_coef_k<<<NN2 / 4, 256, 0, stream>>>(h2, as2, ad2, asn, adn, NN2);
  exscan1_k<<<NN2 / 1024, 1024, 0, stream>>>(deg, scanv, bsum);
  exscan2_k<<<NN2 / 1024, 1024, 0, stream>>>(scanv, bsum, rowst, cursor, NN2 / 1024, NN2);
  csr_fill_p_k<<<NE / 256, 256, 0, stream>>>(ns, nd, cursor, (const float4*)asn,
                                             (const float4*)adn, csrc, pexp, NE);
  gat_agg_k<<<NN2 / 4, 256, 0, stream>>>(h2, (const float4*)asn, (const float4*)adn,
                                         rowst, csrc, pexp, b2, out2, NN2);
  hipMemsetAsync(bnsum, 0, FDIM * 2 * 4, stream);
  stats_k<<<NN2 / 128, 256, 0, stream>>>(out2, bnsum, bnsq, 128);
  bn_finalize_k<<<1, 256, 0, stream>>>(bnsum, bnsq, g2, be2, bnsc, bnsh, 1.0f / NN2);
  bn_score_k<<<NN2 / 4, 256, 0, stream>>>(out2, bnsc, bnsh, pw2, score, NN2);
  // ---------- pool 2 ----------
  topk_k<512, 256><<<NB, 512, 0, stream>>>(score, vals, gidx, nullptr);
  float* xn2 = xn1;
  gather_scale_k<<<NN3, 256, 0, stream>>>(out2, gidx, vals, xn2, nullptr);
  readout_part_k<<<NN3 / RD_ROWS, 256, 0, stream>>>(xn2, pmax, psum, KK2, KK2 / RD_ROWS);
  readout_final_k<<<NB, 256, 0, stream>>>(pmax, psum, x2r, KK2 / RD_ROWS, 1.0f / KK2);
  // ---------- final ----------
  final_k<<<NB, 256, 0, stream>>>(x1r, x2r, Wl, bl, out);
}

// Round 5
// 388.734 us; speedup vs baseline: 1.9998x; 1.0973x over previous
//
#include <hip/hip_runtime.h>

#define NN1 32768
#define NE  262144
#define FDIM 256
#define NHEADS 4
#define HIDC 64
#define IN_DIM 128
#define NB 32
#define KK1 512
#define NN2 16384   // NB*KK1
#define KK2 256
#define NN3 8192    // NB*KK2
#define OUT_DIM 256
#define BN_EPS 1e-5f
#define NEG_SLOPE 0.2f

typedef _Float16 half8 __attribute__((ext_vector_type(8)));
typedef _Float16 half4v __attribute__((ext_vector_type(4)));
typedef float floatx4 __attribute__((ext_vector_type(4)));

__device__ __forceinline__ float lrelu(float x) { return x >= 0.f ? x : NEG_SLOPE * x; }
__device__ __forceinline__ float gelu(float v) {
  return 0.5f * v * (1.0f + erff(v * 0.7071067811865476f));
}

// one-shot zero/init of all accumulator buffers (replaces 5 memsets)
__global__ void zero_k(int* __restrict__ deg1, int* __restrict__ deg2,
                       int* __restrict__ inv1, float* __restrict__ bnstats) {
  int i = blockIdx.x * 256 + threadIdx.x;  // grid = NN1/256
  deg1[i] = 0;
  inv1[i] = -1;
  if (i < NN2) deg2[i] = 0;
  if (i < 1024) bnstats[i] = 0.f;
}

// fp32 -> fp16, 4 elements/thread
__global__ void f32_to_f16_k(const float4* __restrict__ in, half4v* __restrict__ out, int n4) {
  int i = blockIdx.x * blockDim.x + threadIdx.x;
  if (i >= n4) return;
  float4 v = in[i];
  half4v h;
  h[0] = (_Float16)v.x; h[1] = (_Float16)v.y; h[2] = (_Float16)v.z; h[3] = (_Float16)v.w;
  out[i] = h;
}

// B[K][N] fp32 -> BT[N][K] fp16
__global__ void convT_k(const float* __restrict__ B, _Float16* __restrict__ BT,
                        int K, int logK, int N) {
  int idx = blockIdx.x * blockDim.x + threadIdx.x;
  int n = idx >> logK, k = idx & (K - 1);
  BT[idx] = (_Float16)B[k * N + n];
}

// ---------------- MFMA fp16 GEMM: C[M,N](fp16) = A[M,K] * BT[N,K]^T
// block tile 64(M) x 128(N), BK=32, 4 waves 2x2, wave tile 32x64
template <int K>
__global__ void gemm_f16(const _Float16* __restrict__ A, const _Float16* __restrict__ BT,
                         _Float16* __restrict__ C, int N) {
  __shared__ _Float16 As[64 * 40];   // stride 40 halves: <=2-way bank alias (free, m136)
  __shared__ _Float16 Bs[128 * 40];
  int tid = threadIdx.x;
  int lane = tid & 63, w = tid >> 6;
  int bm = blockIdx.y * 64, bn = blockIdx.x * 128;
  int wm = (w & 1) * 32, wn = (w >> 1) * 64;
  floatx4 acc[2][4] = {};
  int ar = tid >> 2, ac = (tid & 3) * 8;
  int br = tid >> 1, bc = (tid & 1) * 16;
  int fm = lane & 15, fq = (lane >> 4) * 8;
  for (int k0 = 0; k0 < K; k0 += 32) {
    __syncthreads();
    *(half8*)&As[ar * 40 + ac] = *(const half8*)&A[(size_t)(bm + ar) * K + k0 + ac];
    *(half8*)&Bs[br * 40 + bc] = *(const half8*)&BT[(size_t)(bn + br) * K + k0 + bc];
    *(half8*)&Bs[br * 40 + bc + 8] = *(const half8*)&BT[(size_t)(bn + br) * K + k0 + bc + 8];
    __syncthreads();
    half8 af[2], bf[4];
#pragma unroll
    for (int mt = 0; mt < 2; ++mt)
      af[mt] = *(const half8*)&As[(wm + mt * 16 + fm) * 40 + fq];
#pragma unroll
    for (int nt = 0; nt < 4; ++nt)
      bf[nt] = *(const half8*)&Bs[(wn + nt * 16 + fm) * 40 + fq];
#pragma unroll
    for (int mt = 0; mt < 2; ++mt)
#pragma unroll
      for (int nt = 0; nt < 4; ++nt)
        acc[mt][nt] = __builtin_amdgcn_mfma_f32_16x16x32_f16(af[mt], bf[nt], acc[mt][nt], 0, 0, 0);
  }
  // C/D: col = lane&15, row = (lane>>4)*4 + reg
  int row0 = bm + wm + (lane >> 4) * 4;
  int col0 = bn + wn + (lane & 15);
#pragma unroll
  for (int mt = 0; mt < 2; ++mt)
#pragma unroll
    for (int nt = 0; nt < 4; ++nt) {
      _Float16* cp = C + (size_t)(row0 + mt * 16) * N + col0 + nt * 16;
#pragma unroll
      for (int i = 0; i < 4; ++i) cp[(size_t)i * N] = (_Float16)acc[mt][nt][i];
    }
}

// per-node attention coefficients from fp16 h
__global__ void attn_coef_k(const _Float16* __restrict__ h, const float* __restrict__ a_s,
                            const float* __restrict__ a_d, float* __restrict__ asn,
                            float* __restrict__ adn, int n) {
  int gid = blockIdx.x * blockDim.x + threadIdx.x;
  int node = gid >> 6, lane = threadIdx.x & 63;
  if (node >= n) return;
  const _Float16* hp = h + (size_t)node * FDIM;
  float ps[NHEADS], pd[NHEADS];
#pragma unroll
  for (int hh = 0; hh < NHEADS; ++hh) {
    float hv = (float)hp[hh * HIDC + lane];
    ps[hh] = hv * a_s[hh * HIDC + lane];
    pd[hh] = hv * a_d[hh * HIDC + lane];
  }
#pragma unroll
  for (int off = 32; off > 0; off >>= 1) {
#pragma unroll
    for (int hh = 0; hh < NHEADS; ++hh) {
      ps[hh] += __shfl_xor(ps[hh], off);
      pd[hh] += __shfl_xor(pd[hh], off);
    }
  }
  if (lane == 0) {
#pragma unroll
    for (int hh = 0; hh < NHEADS; ++hh) {
      asn[node * NHEADS + hh] = ps[hh];
      adn[node * NHEADS + hh] = pd[hh];
    }
  }
}

__global__ void deg_count_k(const int* __restrict__ dst, int* __restrict__ deg, int ne) {
  int e = blockIdx.x * blockDim.x + threadIdx.x;
  if (e < ne) {
    int d = dst[e];
    if (d >= 0) atomicAdd(&deg[d], 1);
  }
}

// 2-level exclusive scan
__global__ void exscan1_k(const int* __restrict__ in, int* __restrict__ outv,
                          int* __restrict__ bsum) {
  __shared__ int wsum[16];
  int tid = threadIdx.x, lane = tid & 63, wv = tid >> 6;
  int base = blockIdx.x * 1024;
  int v = in[base + tid];
  int x = v;
#pragma unroll
  for (int off = 1; off < 64; off <<= 1) {
    int t = __shfl_up(x, off);
    if (lane >= off) x += t;
  }
  if (lane == 63) wsum[wv] = x;
  __syncthreads();
  int woff = 0;
  for (int i = 0; i < wv; i++) woff += wsum[i];
  outv[base + tid] = woff + x - v;
  if (tid == 1023) bsum[blockIdx.x] = woff + x;
}

__global__ void exscan2_k(const int* __restrict__ outv, const int* __restrict__ bsum,
                          int* __restrict__ rowstart, int* __restrict__ cursor,
                          int nblocks, int n) {
  __shared__ int goff;
  int b = blockIdx.x, tid = threadIdx.x;
  if (tid == 0) {
    int s = 0;
    for (int i = 0; i < b; i++) s += bsum[i];
    goff = s;
    if (b == nblocks - 1) rowstart[n] = s + bsum[b];
  }
  __syncthreads();
  int val = outv[b * 1024 + tid] + goff;
  rowstart[b * 1024 + tid] = val;
  cursor[b * 1024 + tid] = val;
}

// CSR fill + per-edge softmax numerator exp(lrelu(asn[s]+adn[d])) (shift-free softmax)
__global__ void csr_fill_p_k(const int* __restrict__ src, const int* __restrict__ dst,
                             int* __restrict__ cursor, const float4* __restrict__ asn4,
                             const float4* __restrict__ adn4, int* __restrict__ csrc,
                             float4* __restrict__ pexp, int ne) {
  int e = blockIdx.x * blockDim.x + threadIdx.x;
  if (e >= ne) return;
  int d = dst[e];
  if (d < 0) return;
  int s = src[e];
  int pos = atomicAdd(&cursor[d], 1);
  csrc[pos] = s;
  float4 a = asn4[s], b = adn4[d];
  float4 p;
  p.x = expf(lrelu(a.x + b.x));
  p.y = expf(lrelu(a.y + b.y));
  p.z = expf(lrelu(a.z + b.z));
  p.w = expf(lrelu(a.w + b.w));
  pexp[pos] = p;
}

// one wave per dst node, single pass over fp16 h; epilogue applies exact GELU
__global__ void gat_agg_k(const _Float16* __restrict__ h, const float4* __restrict__ asn4,
                          const float4* __restrict__ adn4, const int* __restrict__ rowstart,
                          const int* __restrict__ csrc, const float4* __restrict__ pexp,
                          const float* __restrict__ bias, float* __restrict__ out, int n) {
  int lane = threadIdx.x & 63;
  int d = __builtin_amdgcn_readfirstlane(blockIdx.x * 4 + (threadIdx.x >> 6));
  if (d >= n) return;
  int beg = rowstart[d], end = rowstart[d + 1];
  float4 sa = asn4[d], sb = adn4[d];
  float p0 = expf(lrelu(sa.x + sb.x));
  float p1 = expf(lrelu(sa.y + sb.y));
  float p2 = expf(lrelu(sa.z + sb.z));
  float p3 = expf(lrelu(sa.w + sb.w));
  const _Float16* hp = h + (size_t)d * FDIM;
  float de0 = p0, de1 = p1, de2 = p2, de3 = p3;
  float a0 = p0 * (float)hp[lane];
  float a1 = p1 * (float)hp[64 + lane];
  float a2 = p2 * (float)hp[128 + lane];
  float a3 = p3 * (float)hp[192 + lane];
  for (int e = beg; e < end; ++e) {
    int s = csrc[e];
    float4 p = pexp[e];
    const _Float16* hs = h + (size_t)s * FDIM;
    de0 += p.x; de1 += p.y; de2 += p.z; de3 += p.w;
    a0 = fmaf(p.x, (float)hs[lane], a0);
    a1 = fmaf(p.y, (float)hs[64 + lane], a1);
    a2 = fmaf(p.z, (float)hs[128 + lane], a2);
    a3 = fmaf(p.w, (float)hs[192 + lane], a3);
  }
  float* op = out + (size_t)d * FDIM;
  op[lane]       = gelu(a0 / de0 + bias[lane]);
  op[64 + lane]  = gelu(a1 / de1 + bias[64 + lane]);
  op[128 + lane] = gelu(a2 / de2 + bias[128 + lane]);
  op[192 + lane] = gelu(a3 / de3 + bias[192 + lane]);
}

// per-column sum/sumsq partials (post-GELU values)
__global__ void stats_k(const float* __restrict__ x, float* __restrict__ sum,
                        float* __restrict__ sumsq, int rows_per_block) {
  int f = threadIdx.x;
  int r0 = blockIdx.x * rows_per_block;
  float s = 0.f, sq = 0.f;
  for (int r = r0; r < r0 + rows_per_block; ++r) {
    float g = x[(size_t)r * FDIM + f];
    s += g;
    sq += g * g;
  }
  atomicAdd(&sum[f], s);
  atomicAdd(&sumsq[f], sq);
}

// fused BN-finalize + BN-apply (in place) + pooling score; scale/shift recomputed per block
__global__ void bn_score_k(float* __restrict__ x, const float* __restrict__ bnsum,
                           const float* __restrict__ bnsq, const float* __restrict__ g,
                           const float* __restrict__ be, const float* __restrict__ w,
                           float* __restrict__ score, float inv_n, int n) {
  int gid = blockIdx.x * blockDim.x + threadIdx.x;
  int node = gid >> 6, lane = threadIdx.x & 63;
  if (node >= n) return;
  float* xp = x + (size_t)node * FDIM;
  float p = 0.f, nw = 0.f;
#pragma unroll
  for (int j = 0; j < 4; ++j) {
    int c = j * 64 + lane;
    float mean = bnsum[c] * inv_n;
    float var = bnsq[c] * inv_n - mean * mean;
    float sc = g[c] / sqrtf(var + BN_EPS);
    float sh = be[c] - mean * sc;
    float v = fmaf(xp[c], sc, sh);
    xp[c] = v;
    float wv = w[c];
    p = fmaf(v, wv, p);
    nw = fmaf(wv, wv, nw);
  }
#pragma unroll
  for (int off = 32; off > 0; off >>= 1) {
    p += __shfl_xor(p, off);
    nw += __shfl_xor(nw, off);
  }
  if (lane == 0) score[node] = p / sqrtf(nw);
}

// per-graph bitonic sort descending (tie: lower index first); keep first KEEP
template <int NPG_T, int KEEP>
__global__ void topk_k(const float* __restrict__ score, float* __restrict__ vals,
                       int* __restrict__ gidx, int* __restrict__ inv) {
  __shared__ float sv[NPG_T];
  __shared__ int si[NPG_T];
  int tid = threadIdx.x, b = blockIdx.x;
  sv[tid] = score[b * NPG_T + tid];
  si[tid] = tid;
  for (int k = 2; k <= NPG_T; k <<= 1) {
    for (int j = k >> 1; j > 0; j >>= 1) {
      __syncthreads();
      int ixj = tid ^ j;
      if (ixj > tid) {
        float v1 = sv[tid], v2 = sv[ixj];
        int i1 = si[tid], i2 = si[ixj];
        bool before = (v1 > v2) || (v1 == v2 && i1 < i2);
        bool up = ((tid & k) == 0);
        if (up ? !before : before) {
          sv[tid] = v2; sv[ixj] = v1;
          si[tid] = i2; si[ixj] = i1;
        }
      }
    }
  }
  __syncthreads();
  if (tid < KEEP) {
    int gid = b * NPG_T + si[tid];
    int r = b * KEEP + tid;
    vals[r] = sv[tid];
    gidx[r] = gid;
    if (inv) inv[gid] = r;
  }
}

// fused gather + tanh-scale + optional fp16 emit + partial readout (16 rows/block)
// xn fp32 array is ELIMINATED: only fp16 (next GEMM) + readout partials leave this kernel.
template <bool EMIT_F16>
__global__ void pool_gather_k(const float* __restrict__ x, const int* __restrict__ gidx,
                              const float* __restrict__ vals, _Float16* __restrict__ ah,
                              float* __restrict__ pmax, float* __restrict__ psum) {
  int blk = blockIdx.x, f = threadIdx.x;
  int r0 = blk * 16;
  float mx = -3.0e38f, sm = 0.f;
#pragma unroll 4
  for (int j = 0; j < 16; ++j) {
    int r = r0 + j;
    float t = tanhf(vals[r]);
    float v = x[(size_t)gidx[r] * FDIM + f] * t;
    if (EMIT_F16) ah[(size_t)r * FDIM + f] = (_Float16)v;
    mx = fmaxf(mx, v);
    sm += v;
  }
  pmax[(size_t)blk * FDIM + f] = mx;
  psum[(size_t)blk * FDIM + f] = sm;
}

// fused remap + degree count for layer-2 CSR
__global__ void remap_deg_k(const int* __restrict__ src, const int* __restrict__ dst,
                            const int* __restrict__ inv, int* __restrict__ ns,
                            int* __restrict__ nd, int* __restrict__ deg, int ne) {
  int e = blockIdx.x * blockDim.x + threadIdx.x;
  if (e < ne) {
    int a = inv[src[e]], bb = inv[dst[e]];
    bool ok = (a >= 0) && (bb >= 0);
    ns[e] = ok ? a : -1;
    nd[e] = ok ? bb : -1;
    if (ok) atomicAdd(&deg[bb], 1);
  }
}

// fused readout-final (both layers) + output linear
__global__ void final_k(const float* __restrict__ pmax1, const float* __restrict__ psum1,
                        const float* __restrict__ pmax2, const float* __restrict__ psum2,
                        const float* __restrict__ Wl, const float* __restrict__ bl,
                        float* __restrict__ out) {
  __shared__ float xs[2 * FDIM];
  int b = blockIdx.x, f = threadIdx.x;
  float mx1 = -3.0e38f, s1 = 0.f, mx2 = -3.0e38f, s2 = 0.f;
  for (int s = 0; s < KK1 / 16; ++s) {
    mx1 = fmaxf(mx1, pmax1[(size_t)(b * (KK1 / 16) + s) * FDIM + f]);
    s1 += psum1[(size_t)(b * (KK1 / 16) + s) * FDIM + f];
  }
  for (int s = 0; s < KK2 / 16; ++s) {
    mx2 = fmaxf(mx2, pmax2[(size_t)(b * (KK2 / 16) + s) * FDIM + f]);
    s2 += psum2[(size_t)(b * (KK2 / 16) + s) * FDIM + f];
  }
  xs[f] = mx1 + mx2;
  xs[FDIM + f] = s1 * (1.0f / KK1) + s2 * (1.0f / KK2);
  __syncthreads();
  float acc = bl[f];
  const float* wp = Wl + (size_t)f * 512;
  for (int j = 0; j < 512; ++j) acc = fmaf(xs[j], wp[j], acc);
  out[b * OUT_DIM + f] = acc;
}

extern "C" void kernel_launch(void* const* d_in, const int* in_sizes, int n_in,
                              void* d_out, int out_size, void* d_ws, size_t ws_size,
                              hipStream_t stream) {
  (void)in_sizes; (void)n_in; (void)out_size; (void)ws_size;
  const float* x   = (const float*)d_in[0];
  const int* eidx  = (const int*)d_in[1];
  const int* src   = eidx;
  const int* dst   = eidx + NE;
  const float* W1  = (const float*)d_in[3];
  const float* as1 = (const float*)d_in[4];
  const float* ad1 = (const float*)d_in[5];
  const float* b1  = (const float*)d_in[6];
  const float* g1  = (const float*)d_in[7];
  const float* be1 = (const float*)d_in[8];
  const float* pw1 = (const float*)d_in[9];
  const float* W2  = (const float*)d_in[10];
  const float* as2 = (const float*)d_in[11];
  const float* ad2 = (const float*)d_in[12];
  const float* b2  = (const float*)d_in[13];
  const float* g2  = (const float*)d_in[14];
  const float* be2 = (const float*)d_in[15];
  const float* pw2 = (const float*)d_in[16];
  const float* Wl  = (const float*)d_in[17];
  const float* bl  = (const float*)d_in[18];
  float* out = (float*)d_out;

  char* wsp = (char*)d_ws;
  size_t off = 0;
  auto alloc = [&](size_t bytes) -> void* {
    void* p = wsp + off;
    off += (bytes + 255) & ~(size_t)255;
    return p;
  };
  _Float16* h16 = (_Float16*)alloc((size_t)NN1 * FDIM * 2);     // fp16 h (both layers)
  float* out1   = (float*)alloc((size_t)NN1 * FDIM * 4);        // reused as out2
  _Float16* ah  = (_Float16*)alloc((size_t)NN1 * IN_DIM * 2);   // fp16 GEMM A (both layers)
  _Float16* bt  = (_Float16*)alloc((size_t)FDIM * FDIM * 2);    // fp16 B^T
  float* asn    = (float*)alloc((size_t)NN1 * NHEADS * 4);
  float* adn    = (float*)alloc((size_t)NN1 * NHEADS * 4);
  float4* pexp  = (float4*)alloc((size_t)NE * 16);
  int*   deg1   = (int*)alloc((size_t)NN1 * 4);
  int*   deg2   = (int*)alloc((size_t)NN2 * 4);
  int*   rowst  = (int*)alloc((size_t)(NN1 + 1) * 4);
  int*   cursor = (int*)alloc((size_t)NN1 * 4);
  int*   scanv  = (int*)alloc((size_t)NN1 * 4);
  int*   bsum   = (int*)alloc(64 * 4);
  int*   csrc   = (int*)alloc((size_t)NE * 4);
  int*   ns     = (int*)alloc((size_t)NE * 4);
  int*   nd     = (int*)alloc((size_t)NE * 4);
  int*   inv1   = (int*)alloc((size_t)NN1 * 4);
  float* score  = (float*)alloc((size_t)NN1 * 4);
  float* vals   = (float*)alloc((size_t)NN2 * 4);
  int*   gidx   = (int*)alloc((size_t)NN2 * 4);
  float* bnst   = (float*)alloc(1024 * 4);   // [bn1sum|bn1sq|bn2sum|bn2sq] x256
  float* pmax1  = (float*)alloc((size_t)(NN2 / 16) * FDIM * 4);
  float* psum1  = (float*)alloc((size_t)(NN2 / 16) * FDIM * 4);
  float* pmax2  = (float*)alloc((size_t)(NN3 / 16) * FDIM * 4);
  float* psum2  = (float*)alloc((size_t)(NN3 / 16) * FDIM * 4);

  // ---------- init (one launch) ----------
  zero_k<<<NN1 / 256, 256, 0, stream>>>(deg1, deg2, inv1, bnst);
  // ---------- layer 1 ----------
  f32_to_f16_k<<<(NN1 * IN_DIM / 4) / 256, 256, 0, stream>>>((const float4*)x, (half4v*)ah,
                                                             NN1 * IN_DIM / 4);
  convT_k<<<(FDIM * IN_DIM) / 256, 256, 0, stream>>>(W1, bt, IN_DIM, 7, FDIM);
  gemm_f16<IN_DIM><<<dim3(FDIM / 128, NN1 / 64), 256, 0, stream>>>(ah, bt, h16, FDIM);
  attn_coef_k<<<NN1 / 4, 256, 0, stream>>>(h16, as1, ad1, asn, adn, NN1);
  deg_count_k<<<NE / 256, 256, 0, stream>>>(dst, deg1, NE);
  exscan1_k<<<NN1 / 1024, 1024, 0, stream>>>(deg1, scanv, bsum);
  exscan2_k<<<NN1 / 1024, 1024, 0, stream>>>(scanv, bsum, rowst, cursor, NN1 / 1024, NN1);
  csr_fill_p_k<<<NE / 256, 256, 0, stream>>>(src, dst, cursor, (const float4*)asn,
                                             (const float4*)adn, csrc, pexp, NE);
  gat_agg_k<<<NN1 / 4, 256, 0, stream>>>(h16, (const float4*)asn, (const float4*)adn,
                                         rowst, csrc, pexp, b1, out1, NN1);
  stats_k<<<NN1 / 128, 256, 0, stream>>>(out1, bnst, bnst + 256, 128);
  bn_score_k<<<NN1 / 4, 256, 0, stream>>>(out1, bnst, bnst + 256, g1, be1, pw1, score,
                                          1.0f / NN1, NN1);
  // ---------- pool 1 ----------
  topk_k<1024, 512><<<NB, 1024, 0, stream>>>(score, vals, gidx, inv1);
  pool_gather_k<true><<<NN2 / 16, 256, 0, stream>>>(out1, gidx, vals, ah, pmax1, psum1);
  remap_deg_k<<<NE / 256, 256, 0, stream>>>(src, dst, inv1, ns, nd, deg2, NE);
  // ---------- layer 2 ----------
  convT_k<<<(FDIM * FDIM) / 256, 256, 0, stream>>>(W2, bt, FDIM, 8, FDIM);
  gemm_f16<FDIM><<<dim3(FDIM / 128, NN2 / 64), 256, 0, stream>>>(ah, bt, h16, FDIM);
  attn_coef_k<<<NN2 / 4, 256, 0, stream>>>(h16, as2, ad2, asn, adn, NN2);
  exscan1_k<<<NN2 / 1024, 1024, 0, stream>>>(deg2, scanv, bsum);
  exscan2_k<<<NN2 / 1024, 1024, 0, stream>>>(scanv, bsum, rowst, cursor, NN2 / 1024, NN2);
  csr_fill_p_k<<<NE / 256, 256, 0, stream>>>(ns, nd, cursor, (const float4*)asn,
                                             (const float4*)adn, csrc, pexp, NE);
  float* out2 = out1;
  gat_agg_k<<<NN2 / 4, 256, 0, stream>>>(h16, (const float4*)asn, (const float4*)adn,
                                         rowst, csrc, pexp, b2, out2, NN2);
  stats_k<<<NN2 / 128, 256, 0, stream>>>(out2, bnst + 512, bnst + 768, 128);
  bn_score_k<<<NN2 / 4, 256, 0, stream>>>(out2, bnst + 512, bnst + 768, g2, be2, pw2, score,
                                          1.0f / NN2, NN2);
  // ---------- pool 2 ----------
  topk_k<512, 256><<<NB, 512, 0, stream>>>(score, vals, gidx, nullptr);
  pool_gather_k<false><<<NN3 / 16, 256, 0, stream>>>(out2, gidx, vals, nullptr, pmax2, psum2);
  // ---------- final (fused readout-final + linear) ----------
  final_k<<<NB, 256, 0, stream>>>(pmax1, psum1, pmax2, psum2, Wl, bl, out);
}